// Round 1
// baseline (1790.760 us; speedup 1.0000x reference)
//
#include <hip/hip_runtime.h>
#include <math.h>

#define NN 50000
#define NE 800000
#define NG 1024
#define HID 128

__device__ __forceinline__ float leakyf(float v){ return v >= 0.f ? v : 0.01f*v; }
__device__ __forceinline__ float sigmf(float v){ return 1.f/(1.f+expf(-v)); }
__device__ __forceinline__ float eluf(float v){ return v > 0.f ? v : expm1f(v); }

// ---------------- generic fp32 GEMM: C[r,m] = act(sum_k A[r,k]*W[m,k] + bias[m]) ----
// A: rows x K row-major; W: M x K row-major; C: rows x M. grid = (M/64, ceil(rows/64))
template<int K>
__global__ __launch_bounds__(256)
void gemm_nt(const float* __restrict__ A, const float* __restrict__ W,
             const float* __restrict__ bias, float* __restrict__ C,
             int rows, int M, int act)
{
  __shared__ float As[16][68];
  __shared__ float Ws[16][68];
  const int bm = blockIdx.x * 64;
  const int bn = blockIdx.y * 64;
  const int tid = (int)threadIdx.x;
  const int tx = tid & 15, ty = tid >> 4;
  const int lrow = tid >> 2;          // 0..63
  const int lk   = (tid & 3) << 2;    // 0,4,8,12
  const int arow = bn + lrow;
  float acc[4][4] = {{0.f,0.f,0.f,0.f},{0.f,0.f,0.f,0.f},{0.f,0.f,0.f,0.f},{0.f,0.f,0.f,0.f}};
  for (int k0 = 0; k0 < K; k0 += 16) {
    float4 av = make_float4(0.f,0.f,0.f,0.f);
    if (arow < rows) av = *(const float4*)(A + (size_t)arow*K + k0 + lk);
    float4 wv = *(const float4*)(W + (size_t)(bm+lrow)*K + k0 + lk);
    __syncthreads();
    As[lk+0][lrow]=av.x; As[lk+1][lrow]=av.y; As[lk+2][lrow]=av.z; As[lk+3][lrow]=av.w;
    Ws[lk+0][lrow]=wv.x; Ws[lk+1][lrow]=wv.y; Ws[lk+2][lrow]=wv.z; Ws[lk+3][lrow]=wv.w;
    __syncthreads();
#pragma unroll
    for (int kk = 0; kk < 16; ++kk) {
      float4 a = *(const float4*)&As[kk][ty<<2];
      float4 b = *(const float4*)&Ws[kk][tx<<2];
      acc[0][0] += a.x*b.x; acc[0][1] += a.x*b.y; acc[0][2] += a.x*b.z; acc[0][3] += a.x*b.w;
      acc[1][0] += a.y*b.x; acc[1][1] += a.y*b.y; acc[1][2] += a.y*b.z; acc[1][3] += a.y*b.w;
      acc[2][0] += a.z*b.x; acc[2][1] += a.z*b.y; acc[2][2] += a.z*b.z; acc[2][3] += a.z*b.w;
      acc[3][0] += a.w*b.x; acc[3][1] += a.w*b.y; acc[3][2] += a.w*b.z; acc[3][3] += a.w*b.w;
    }
  }
  float4 bv = make_float4(0.f,0.f,0.f,0.f);
  if (bias) bv = *(const float4*)(bias + bm + (tx<<2));
#pragma unroll
  for (int i=0;i<4;i++){
    int r = bn + (ty<<2) + i;
    if (r < rows) {
      float4 o;
      o.x = acc[i][0] + bv.x; o.y = acc[i][1] + bv.y;
      o.z = acc[i][2] + bv.z; o.w = acc[i][3] + bv.w;
      if (act==1){ o.x=leakyf(o.x); o.y=leakyf(o.y); o.z=leakyf(o.z); o.w=leakyf(o.w); }
      *(float4*)(C + (size_t)r*M + bm + (tx<<2)) = o;
    }
  }
}

// ---------------- out[r] = dot(A[r,0:128], v) + (bias?bias[0]:0) ---------------------
__global__ __launch_bounds__(256)
void rowdot(const float* __restrict__ A, const float* __restrict__ v,
            const float* __restrict__ bias, float* __restrict__ out, int rows)
{
  int wave = (int)((blockIdx.x * blockDim.x + threadIdx.x) >> 6);
  int lane = (int)(threadIdx.x & 63);
  if (wave >= rows) return;
  float2 a  = ((const float2*)(A + (size_t)wave*HID))[lane];
  float2 vv = ((const float2*)v)[lane];
  float s = a.x*vv.x + a.y*vv.y;
  for (int off=32; off; off>>=1) s += __shfl_down(s, off);
  if (lane==0) out[wave] = s + (bias ? bias[0] : 0.f);
}

// ---------------- CSR build ----------------------------------------------------------
__global__ void count_kernel(const int* __restrict__ idx, int* __restrict__ cnt, int n){
  int i = (int)(blockIdx.x*blockDim.x + threadIdx.x);
  if (i < n) atomicAdd(&cnt[idx[i]], 1);
}

__global__ __launch_bounds__(1024)
void scan_kernel(const int* __restrict__ cnt, int* __restrict__ off, int n){
  __shared__ int buf[1024];
  __shared__ int carry;
  if (threadIdx.x==0) carry = 0;
  __syncthreads();
  for (int base=0; base<n; base+=1024){
    int i = base + (int)threadIdx.x;
    int v = (i<n)? cnt[i] : 0;
    buf[threadIdx.x] = v;
    __syncthreads();
    for (int s=1;s<1024;s<<=1){
      int t = ((int)threadIdx.x >= s) ? buf[threadIdx.x - s] : 0;
      __syncthreads();
      buf[threadIdx.x] += t;
      __syncthreads();
    }
    if (i<n) off[i] = carry + buf[threadIdx.x] - v;   // exclusive prefix
    int total = buf[1023];
    __syncthreads();
    if (threadIdx.x==0) carry += total;
    __syncthreads();
  }
  if (threadIdx.x==0) off[n] = carry;
}

__global__ void fill_kernel(const int* __restrict__ src, const int* __restrict__ dst,
                            const int* __restrict__ off, int* __restrict__ fill,
                            int* __restrict__ ssrc, int n){
  int e = (int)(blockIdx.x*blockDim.x + threadIdx.x);
  if (e < n){
    int d = dst[e];
    int p = off[d] + atomicAdd(&fill[d], 1);
    ssrc[p] = src[e];
  }
}

// ---------------- pack Wg1[:, :128] and cg = rowsum(Wg1[:,128:153]) ------------------
__global__ void prep_gate(const float* __restrict__ Wg1, float* __restrict__ Wp,
                          float* __restrict__ cg){
  int j = (int)blockIdx.x;      // 128 rows
  int t = (int)threadIdx.x;     // 128 threads
  Wp[j*128 + t] = Wg1[j*153 + t];
  if (t == 0){
    float s = 0.f;
    for (int k=128;k<153;k++) s += Wg1[j*153+k];
    cg[j] = s;
  }
}

// ---------------- per-dst softmax + weighted gather-sum + elu(+bias) -----------------
// one wave per dst node; logit_e = leaky(ls[src]+ld[dst]); out = elu(sum a_e*M[src] + bias)
__global__ __launch_bounds__(256)
void agg_edges(const int* __restrict__ off, const int* __restrict__ ssrc,
               const float* __restrict__ ls, const float* __restrict__ ld,
               const float* __restrict__ Mrows, const float* __restrict__ bias,
               float* __restrict__ out, int n)
{
  int node = (int)((blockIdx.x * blockDim.x + threadIdx.x) >> 6);
  int lane = (int)(threadIdx.x & 63);
  if (node >= n) return;
  int e0 = off[node], e1 = off[node+1];
  float ldv = ld[node];
  float s = 0.f;
  for (int j=e0;j<e1;j++){
    int sc = ssrc[j];
    s += expf(leakyf(ls[sc]+ldv));
  }
  float inv = 1.f/(s + 1e-16f);
  float2 acc = make_float2(0.f,0.f);
  for (int j=e0;j<e1;j++){
    int sc = ssrc[j];
    float a = expf(leakyf(ls[sc]+ldv)) * inv;
    float2 m = ((const float2*)(Mrows + (size_t)sc*HID))[lane];
    acc.x += a*m.x; acc.y += a*m.y;
  }
  float2 b = ((const float2*)bias)[lane];
  float2 o;
  o.x = eluf(acc.x + b.x);
  o.y = eluf(acc.y + b.y);
  ((float2*)(out + (size_t)node*HID))[lane] = o;
}

// ---------------- GRU combine + relu (in-place capable) ------------------------------
// gi = inp@Wih.T+bih (rows x 384), gh = h@Whh.T+bhh, h = previous state (rows x 128)
__global__ __launch_bounds__(256)
void gru_combine(const float* __restrict__ gi, const float* __restrict__ gh,
                 const float* __restrict__ h, float* __restrict__ out, int rows)
{
  int i = (int)(blockIdx.x*blockDim.x + threadIdx.x);
  if (i >= rows*HID) return;
  int r = i >> 7, c = i & 127;
  const float* gir = gi + (size_t)r*384;
  const float* ghr = gh + (size_t)r*384;
  float rr = sigmf(gir[c]       + ghr[c]);
  float zz = sigmf(gir[c+128]   + ghr[c+128]);
  float nn = tanhf(gir[c+256] + rr*ghr[c+256]);
  float hv = h[i];
  float v = (1.f - zz)*nn + zz*hv;
  out[i] = fmaxf(v, 0.f);
}

// ---------------- readout: out[g] = relu(sum_{n in g} X[n]) --------------------------
__global__ __launch_bounds__(256)
void graph_sum(const int* __restrict__ goff, const float* __restrict__ X,
               float* __restrict__ out)
{
  int g = (int)((blockIdx.x*blockDim.x + threadIdx.x) >> 6);
  int lane = (int)(threadIdx.x & 63);
  if (g >= NG) return;
  float2 acc = make_float2(0.f,0.f);
  for (int n=goff[g]; n<goff[g+1]; ++n){
    float2 v = ((const float2*)(X + (size_t)n*HID))[lane];
    acc.x += v.x; acc.y += v.y;
  }
  ((float2*)(out + (size_t)g*HID))[lane] = make_float2(fmaxf(acc.x,0.f), fmaxf(acc.y,0.f));
}

// ---------------- readout attention aggregate ----------------------------------------
__global__ __launch_bounds__(256)
void graph_soft(const int* __restrict__ goff, const float* __restrict__ asrc,
                const float* __restrict__ adst, const float* __restrict__ Xt,
                const float* __restrict__ bias, float* __restrict__ out)
{
  int g = (int)((blockIdx.x*blockDim.x + threadIdx.x) >> 6);
  int lane = (int)(threadIdx.x & 63);
  if (g >= NG) return;
  int n0 = goff[g], n1 = goff[g+1];
  float ad = adst[g];
  float s = 0.f;
  for (int n=n0;n<n1;++n) s += expf(leakyf(asrc[n]+ad));
  float inv = 1.f/(s + 1e-16f);
  float2 acc = make_float2(0.f,0.f);
  for (int n=n0;n<n1;++n){
    float a = expf(leakyf(asrc[n]+ad)) * inv;
    float2 v = ((const float2*)(Xt + (size_t)n*HID))[lane];
    acc.x += a*v.x; acc.y += a*v.y;
  }
  float2 b = ((const float2*)bias)[lane];
  ((float2*)(out + (size_t)g*HID))[lane] = make_float2(eluf(acc.x+b.x), eluf(acc.y+b.y));
}

// =====================================================================================
extern "C" void kernel_launch(void* const* d_in, const int* in_sizes, int n_in,
                              void* d_out, int out_size, void* d_ws, size_t ws_size,
                              hipStream_t stream)
{
  const float* x_in  = (const float*)d_in[0];
  const int*   ei    = (const int*)d_in[1];
  const int*   batch = (const int*)d_in[2];
  const float* W1    = (const float*)d_in[3];
  const float* b1    = (const float*)d_in[4];
  const float* Wg1   = (const float*)d_in[5];
  const float* att_l = (const float*)d_in[6];
  const float* att_r = (const float*)d_in[7];
  const float* Wg2   = (const float*)d_in[8];
  const float* bg    = (const float*)d_in[9];
  const float* Wih0  = (const float*)d_in[10];
  const float* Whh0  = (const float*)d_in[11];
  const float* bih0  = (const float*)d_in[12];
  const float* bhh0  = (const float*)d_in[13];
  const float* Wa    = (const float*)d_in[14];
  const float* att_src_a = (const float*)d_in[15];
  const float* att_dst_a = (const float*)d_in[16];
  const float* ba    = (const float*)d_in[17];
  const float* Wih_a = (const float*)d_in[18];
  const float* Whh_a = (const float*)d_in[19];
  const float* bih_a = (const float*)d_in[20];
  const float* bhh_a = (const float*)d_in[21];
  const float* Wm    = (const float*)d_in[22];
  const float* att_src_m = (const float*)d_in[23];
  const float* att_dst_m = (const float*)d_in[24];
  const float* bm    = (const float*)d_in[25];
  const float* Wih_m = (const float*)d_in[26];
  const float* Whh_m = (const float*)d_in[27];
  const float* bih_m = (const float*)d_in[28];
  const float* bhh_m = (const float*)d_in[29];
  const float* W2    = (const float*)d_in[30];
  const float* b2    = (const float*)d_in[31];
  (void)in_sizes; (void)n_in; (void)out_size; (void)ws_size;

  // ---- workspace layout (256B aligned blocks) ----
  char* wsb = (char*)d_ws;
  size_t off = 0;
  auto alloc = [&](size_t bytes)->void* {
    void* p = wsb + off;
    off += (bytes + 255) & ~(size_t)255;
    return p;
  };
  const int CH = 25000;   // GRU row chunk (NN = 2*CH)
  float* f_x   = (float*)alloc((size_t)NN*HID*4);
  float* f_h   = (float*)alloc((size_t)NN*HID*4);
  float* f_t   = (float*)alloc((size_t)NN*HID*4);
  float* f_s1  = (float*)alloc((size_t)NN*4);
  float* f_s2  = (float*)alloc((size_t)NN*4);
  float* f_gi  = (float*)alloc((size_t)CH*384*4);
  float* f_gh  = (float*)alloc((size_t)CH*384*4);
  float* g_out = (float*)alloc((size_t)NG*HID*4);
  float* g_ot  = (float*)alloc((size_t)NG*HID*4);
  float* g_h   = (float*)alloc((size_t)NG*HID*4);
  float* g_adst= (float*)alloc((size_t)NG*4);
  float* g_gi  = (float*)alloc((size_t)NG*384*4);
  float* g_gh  = (float*)alloc((size_t)NG*384*4);
  float* w_g1p = (float*)alloc((size_t)HID*HID*4);
  float* w_cg  = (float*)alloc((size_t)HID*4);
  int* i_cnt   = (int*)alloc((size_t)NN*4);
  int* i_off   = (int*)alloc((size_t)(NN+1)*4);
  int* i_fill  = (int*)alloc((size_t)NN*4);
  int* i_src   = (int*)alloc((size_t)NE*4);
  int* i_gcnt  = (int*)alloc((size_t)NG*4);
  int* i_goff  = (int*)alloc((size_t)(NG+1)*4);

  const int* e_src = ei;
  const int* e_dst = ei + NE;

  hipMemsetAsync(i_cnt, 0, (size_t)NN*4, stream);
  hipMemsetAsync(i_fill, 0, (size_t)NN*4, stream);
  hipMemsetAsync(i_gcnt, 0, (size_t)NG*4, stream);

  // CSR over dst; graph offsets over (sorted) batch
  count_kernel<<<(NE+255)/256,256,0,stream>>>(e_dst, i_cnt, NE);
  scan_kernel<<<1,1024,0,stream>>>(i_cnt, i_off, NN);
  fill_kernel<<<(NE+255)/256,256,0,stream>>>(e_src, e_dst, i_off, i_fill, i_src, NE);
  count_kernel<<<(NN+255)/256,256,0,stream>>>(batch, i_gcnt, NN);
  scan_kernel<<<1,1024,0,stream>>>(i_gcnt, i_goff, NG);
  prep_gate<<<128,128,0,stream>>>(Wg1, w_g1p, w_cg);

  const int rb = (NN+63)/64;                 // row blocks for N nodes
  const int wavegrid_n = (NN*64+255)/256;    // one wave per node
  const int wavegrid_g = (NG*64)/256;        // one wave per graph

  // x = leaky(x @ W1.T + b1)
  gemm_nt<64><<<dim3(2,rb),256,0,stream>>>(x_in, W1, b1, f_x, NN, HID, 1);

  // ---- GATEConv ----
  gemm_nt<128><<<dim3(2,rb),256,0,stream>>>(f_x, w_g1p, w_cg, f_t, NN, HID, 1);   // xe (per-node)
  rowdot<<<wavegrid_n,256,0,stream>>>(f_t, att_l, nullptr, f_s1, NN);             // el
  rowdot<<<wavegrid_n,256,0,stream>>>(f_x, att_r, nullptr, f_s2, NN);             // er
  gemm_nt<128><<<dim3(2,rb),256,0,stream>>>(f_x, Wg2, nullptr, f_t, NN, HID, 0);  // xg2
  agg_edges<<<(NN+3)/4,256,0,stream>>>(i_off, i_src, f_s1, f_s2, f_t, bg, f_h, NN);
  for (int c0=0;c0<NN;c0+=CH){
    gemm_nt<128><<<dim3(6,(CH+63)/64),256,0,stream>>>(f_h + (size_t)c0*HID, Wih0, bih0, f_gi, CH, 384, 0);
    gemm_nt<128><<<dim3(6,(CH+63)/64),256,0,stream>>>(f_x + (size_t)c0*HID, Whh0, bhh0, f_gh, CH, 384, 0);
    gru_combine<<<(CH*HID+255)/256,256,0,stream>>>(f_gi, f_gh, f_x+(size_t)c0*HID, f_x+(size_t)c0*HID, CH);
  }

  // ---- 2x GATConv + GRU ----
  for (int l=0;l<2;l++){
    gemm_nt<128><<<dim3(2,rb),256,0,stream>>>(f_x, Wa + (size_t)l*HID*HID, nullptr, f_t, NN, HID, 0);
    rowdot<<<wavegrid_n,256,0,stream>>>(f_t, att_src_a + l*HID, nullptr, f_s1, NN);
    rowdot<<<wavegrid_n,256,0,stream>>>(f_t, att_dst_a + l*HID, nullptr, f_s2, NN);
    agg_edges<<<(NN+3)/4,256,0,stream>>>(i_off, i_src, f_s1, f_s2, f_t, ba + l*HID, f_h, NN);
    for (int c0=0;c0<NN;c0+=CH){
      gemm_nt<128><<<dim3(6,(CH+63)/64),256,0,stream>>>(f_h + (size_t)c0*HID, Wih_a + (size_t)l*384*HID, bih_a + l*384, f_gi, CH, 384, 0);
      gemm_nt<128><<<dim3(6,(CH+63)/64),256,0,stream>>>(f_x + (size_t)c0*HID, Whh_a + (size_t)l*384*HID, bhh_a + l*384, f_gh, CH, 384, 0);
      gru_combine<<<(CH*HID+255)/256,256,0,stream>>>(f_gi, f_gh, f_x+(size_t)c0*HID, f_x+(size_t)c0*HID, CH);
    }
  }

  // ---- attentive readout ----
  graph_sum<<<wavegrid_g,256,0,stream>>>(i_goff, f_x, g_out);
  gemm_nt<128><<<dim3(2,rb),256,0,stream>>>(f_x, Wm, nullptr, f_t, NN, HID, 0);   // xt (nodes)
  rowdot<<<wavegrid_n,256,0,stream>>>(f_t, att_src_m, nullptr, f_s1, NN);         // a_src
  for (int t=0;t<3;t++){
    gemm_nt<128><<<dim3(2,(NG+63)/64),256,0,stream>>>(g_out, Wm, nullptr, g_ot, NG, HID, 0);
    rowdot<<<wavegrid_g,256,0,stream>>>(g_ot, att_dst_m, nullptr, g_adst, NG);
    graph_soft<<<wavegrid_g,256,0,stream>>>(i_goff, f_s1, g_adst, f_t, bm, g_h);
    gemm_nt<128><<<dim3(6,(NG+63)/64),256,0,stream>>>(g_h, Wih_m, bih_m, g_gi, NG, 384, 0);
    gemm_nt<128><<<dim3(6,(NG+63)/64),256,0,stream>>>(g_out, Whh_m, bhh_m, g_gh, NG, 384, 0);
    gru_combine<<<(NG*HID+255)/256,256,0,stream>>>(g_gi, g_gh, g_out, g_out, NG);
  }

  // final: d_out[g] = dot(out[g], W2) + b2
  rowdot<<<wavegrid_g,256,0,stream>>>(g_out, W2, b2, (float*)d_out, NG);
}

// Round 2
// 1366.153 us; speedup vs baseline: 1.3108x; 1.3108x over previous
//
#include <hip/hip_runtime.h>
#include <math.h>

#define NN 50000
#define NE 800000
#define NG 1024
#define HID 128

__device__ __forceinline__ float leakyf(float v){ return v >= 0.f ? v : 0.01f*v; }
__device__ __forceinline__ float sigmf(float v){ return 1.f/(1.f+expf(-v)); }
__device__ __forceinline__ float eluf(float v){ return v > 0.f ? v : expm1f(v); }

// ================= big fp32 GEMM: 128x128 tile, 8x8 regs =============================
// C[r,m] = act(sum_k A[r,k]*W[m,k] + bias[m]); A rows x K, W M x K, row-major.
// grid = (M/128, ceil(rows/128)), block = 256
template<int K>
__global__ __launch_bounds__(256)
void gemm_big(const float* __restrict__ A, const float* __restrict__ W,
              const float* __restrict__ bias, float* __restrict__ C,
              int rows, int M, int act)
{
  __shared__ float As[16][132];
  __shared__ float Ws[16][132];
  const int bm = blockIdx.x * 128;
  const int bn = blockIdx.y * 128;
  const int tid = (int)threadIdx.x;
  const int tx = tid & 15;      // col group: 8 cols
  const int ty = tid >> 4;      // row group: 8 rows
  const int sr = tid >> 1;      // staging row 0..127
  const int sk = (tid & 1) * 8; // staging k 0 or 8
  float acc[8][8] = {};
  for (int k0 = 0; k0 < K; k0 += 16) {
    float4 a0 = make_float4(0,0,0,0), a1 = make_float4(0,0,0,0);
    int ar = bn + sr;
    if (ar < rows) {
      a0 = *(const float4*)(A + (size_t)ar*K + k0 + sk);
      a1 = *(const float4*)(A + (size_t)ar*K + k0 + sk + 4);
    }
    float4 w0 = *(const float4*)(W + (size_t)(bm+sr)*K + k0 + sk);
    float4 w1 = *(const float4*)(W + (size_t)(bm+sr)*K + k0 + sk + 4);
    __syncthreads();
    As[sk+0][sr]=a0.x; As[sk+1][sr]=a0.y; As[sk+2][sr]=a0.z; As[sk+3][sr]=a0.w;
    As[sk+4][sr]=a1.x; As[sk+5][sr]=a1.y; As[sk+6][sr]=a1.z; As[sk+7][sr]=a1.w;
    Ws[sk+0][sr]=w0.x; Ws[sk+1][sr]=w0.y; Ws[sk+2][sr]=w0.z; Ws[sk+3][sr]=w0.w;
    Ws[sk+4][sr]=w1.x; Ws[sk+5][sr]=w1.y; Ws[sk+6][sr]=w1.z; Ws[sk+7][sr]=w1.w;
    __syncthreads();
#pragma unroll
    for (int kk = 0; kk < 16; ++kk) {
      float4 av0 = *(const float4*)&As[kk][ty*8];
      float4 av1 = *(const float4*)&As[kk][ty*8+4];
      float4 bv0 = *(const float4*)&Ws[kk][tx*8];
      float4 bv1 = *(const float4*)&Ws[kk][tx*8+4];
      float a[8] = {av0.x,av0.y,av0.z,av0.w,av1.x,av1.y,av1.z,av1.w};
      float b[8] = {bv0.x,bv0.y,bv0.z,bv0.w,bv1.x,bv1.y,bv1.z,bv1.w};
#pragma unroll
      for (int i=0;i<8;i++)
#pragma unroll
        for (int j=0;j<8;j++) acc[i][j] += a[i]*b[j];
    }
  }
  float bb[8] = {0,0,0,0,0,0,0,0};
  if (bias) {
    float4 b0 = *(const float4*)(bias + bm + tx*8);
    float4 b1 = *(const float4*)(bias + bm + tx*8 + 4);
    bb[0]=b0.x; bb[1]=b0.y; bb[2]=b0.z; bb[3]=b0.w;
    bb[4]=b1.x; bb[5]=b1.y; bb[6]=b1.z; bb[7]=b1.w;
  }
#pragma unroll
  for (int i=0;i<8;i++){
    int r = bn + ty*8 + i;
    if (r < rows){
      float o[8];
#pragma unroll
      for (int j=0;j<8;j++){
        float v = acc[i][j] + bb[j];
        o[j] = (act==1) ? leakyf(v) : v;
      }
      *(float4*)(C + (size_t)r*M + bm + tx*8)     = make_float4(o[0],o[1],o[2],o[3]);
      *(float4*)(C + (size_t)r*M + bm + tx*8 + 4) = make_float4(o[4],o[5],o[6],o[7]);
    }
  }
}

// ================= small fp32 GEMM (64x64 tile) for rows~1024 ========================
template<int K>
__global__ __launch_bounds__(256)
void gemm_nt(const float* __restrict__ A, const float* __restrict__ W,
             const float* __restrict__ bias, float* __restrict__ C,
             int rows, int M, int act)
{
  __shared__ float As[16][68];
  __shared__ float Ws[16][68];
  const int bm = blockIdx.x * 64;
  const int bn = blockIdx.y * 64;
  const int tid = (int)threadIdx.x;
  const int tx = tid & 15, ty = tid >> 4;
  const int lrow = tid >> 2;
  const int lk   = (tid & 3) << 2;
  const int arow = bn + lrow;
  float acc[4][4] = {};
  for (int k0 = 0; k0 < K; k0 += 16) {
    float4 av = make_float4(0,0,0,0);
    if (arow < rows) av = *(const float4*)(A + (size_t)arow*K + k0 + lk);
    float4 wv = *(const float4*)(W + (size_t)(bm+lrow)*K + k0 + lk);
    __syncthreads();
    As[lk+0][lrow]=av.x; As[lk+1][lrow]=av.y; As[lk+2][lrow]=av.z; As[lk+3][lrow]=av.w;
    Ws[lk+0][lrow]=wv.x; Ws[lk+1][lrow]=wv.y; Ws[lk+2][lrow]=wv.z; Ws[lk+3][lrow]=wv.w;
    __syncthreads();
#pragma unroll
    for (int kk = 0; kk < 16; ++kk) {
      float4 a = *(const float4*)&As[kk][ty<<2];
      float4 b = *(const float4*)&Ws[kk][tx<<2];
      float av_[4]={a.x,a.y,a.z,a.w}, bv_[4]={b.x,b.y,b.z,b.w};
#pragma unroll
      for(int i=0;i<4;i++)
#pragma unroll
        for(int j=0;j<4;j++) acc[i][j]+=av_[i]*bv_[j];
    }
  }
  float4 bv = make_float4(0,0,0,0);
  if (bias) bv = *(const float4*)(bias + bm + (tx<<2));
#pragma unroll
  for (int i=0;i<4;i++){
    int r = bn + (ty<<2) + i;
    if (r < rows) {
      float4 o;
      o.x = acc[i][0]+bv.x; o.y = acc[i][1]+bv.y; o.z = acc[i][2]+bv.z; o.w = acc[i][3]+bv.w;
      if (act==1){ o.x=leakyf(o.x); o.y=leakyf(o.y); o.z=leakyf(o.z); o.w=leakyf(o.w); }
      *(float4*)(C + (size_t)r*M + bm + (tx<<2)) = o;
    }
  }
}

// ================= rowdots ===========================================================
__global__ __launch_bounds__(256)
void rowdot(const float* __restrict__ A, const float* __restrict__ v,
            const float* __restrict__ bias, float* __restrict__ out, int rows)
{
  int wave = (int)((blockIdx.x * blockDim.x + threadIdx.x) >> 6);
  int lane = (int)(threadIdx.x & 63);
  if (wave >= rows) return;
  float2 a  = ((const float2*)(A + (size_t)wave*HID))[lane];
  float2 vv = ((const float2*)v)[lane];
  float s = a.x*vv.x + a.y*vv.y;
  for (int off=32; off; off>>=1) s += __shfl_down(s, off);
  if (lane==0) out[wave] = s + (bias ? bias[0] : 0.f);
}

__global__ __launch_bounds__(256)
void rowdot2(const float* __restrict__ A, const float* __restrict__ v1,
             const float* __restrict__ B, const float* __restrict__ v2,
             float* __restrict__ o1, float* __restrict__ o2, int rows)
{
  int wave = (int)((blockIdx.x * blockDim.x + threadIdx.x) >> 6);
  int lane = (int)(threadIdx.x & 63);
  if (wave >= rows) return;
  float2 a  = ((const float2*)(A + (size_t)wave*HID))[lane];
  float2 b  = ((const float2*)(B + (size_t)wave*HID))[lane];
  float2 w1 = ((const float2*)v1)[lane];
  float2 w2 = ((const float2*)v2)[lane];
  float s1 = a.x*w1.x + a.y*w1.y;
  float s2 = b.x*w2.x + b.y*w2.y;
  for (int off=32; off; off>>=1){ s1 += __shfl_down(s1, off); s2 += __shfl_down(s2, off); }
  if (lane==0){ o1[wave]=s1; o2[wave]=s2; }
}

// out[k] = sum_j W[j,k]*v[j]   (W: 128x128)
__global__ void colvec(const float* __restrict__ W, const float* __restrict__ v,
                       float* __restrict__ out)
{
  int k = (int)threadIdx.x;
  float s = 0.f;
  for (int j=0;j<HID;j++) s += W[j*HID+k]*v[j];
  out[k] = s;
}

// ================= CSR build (grid-parallel scan) ====================================
__global__ void count_kernel(const int* __restrict__ idx, int* __restrict__ cnt, int n){
  int i = (int)(blockIdx.x*blockDim.x + threadIdx.x);
  if (i < n) atomicAdd(&cnt[idx[i]], 1);
}

__global__ __launch_bounds__(1024)
void scan_blocks(const int* __restrict__ cnt, int* __restrict__ off,
                 int* __restrict__ tot, int n)
{
  __shared__ int buf[1024];
  int i = (int)(blockIdx.x*1024 + threadIdx.x);
  int v = (i<n)? cnt[i] : 0;
  buf[threadIdx.x] = v;
  __syncthreads();
  for (int s=1;s<1024;s<<=1){
    int t = ((int)threadIdx.x >= s) ? buf[threadIdx.x - s] : 0;
    __syncthreads();
    buf[threadIdx.x] += t;
    __syncthreads();
  }
  if (i<n) off[i] = buf[threadIdx.x] - v;   // block-local exclusive
  if (threadIdx.x==1023) tot[blockIdx.x] = buf[1023];
}

// one wave; nb <= 64: exclusive-scan tot in place, write grand total to off_end
__global__ void scan_tot(int* __restrict__ tot, int* __restrict__ off_end, int nb){
  int lane = (int)threadIdx.x;
  int orig = (lane<nb)? tot[lane] : 0;
  int v = orig;
  for (int s=1;s<64;s<<=1){ int t = __shfl_up(v, s); if (lane>=s) v += t; }
  int total = __shfl(v, 63);
  if (lane<nb) tot[lane] = v - orig;
  if (lane==0) *off_end = total;
}

__global__ void scan_add(int* __restrict__ off, const int* __restrict__ tot, int n){
  int i = (int)(blockIdx.x*blockDim.x + threadIdx.x);
  if (i<n) off[i] += tot[i>>10];
}

__global__ void fill_kernel(const int* __restrict__ src, const int* __restrict__ dst,
                            const int* __restrict__ off, int* __restrict__ fill,
                            int* __restrict__ ssrc, int n){
  int e = (int)(blockIdx.x*blockDim.x + threadIdx.x);
  if (e < n){
    int d = dst[e];
    int p = off[d] + atomicAdd(&fill[d], 1);
    ssrc[p] = src[e];
  }
}

// goff[g] = first n with batch[n] >= g (batch sorted)
__global__ void graph_bounds(const int* __restrict__ batch, int* __restrict__ goff){
  int g = (int)(blockIdx.x*blockDim.x + threadIdx.x);
  if (g > NG) return;
  int lo=0, hi=NN;
  while (lo<hi){ int mid=(lo+hi)>>1; if (batch[mid] < g) lo=mid+1; else hi=mid; }
  goff[g] = lo;
}

// ================= pack Wg1[:, :128] and cg = rowsum(Wg1[:,128:153]) =================
__global__ void prep_gate(const float* __restrict__ Wg1, float* __restrict__ Wp,
                          float* __restrict__ cg){
  int j = (int)blockIdx.x;
  int t = (int)threadIdx.x;
  Wp[j*128 + t] = Wg1[j*153 + t];
  if (t == 0){
    float s = 0.f;
    for (int k=128;k<153;k++) s += Wg1[j*153+k];
    cg[j] = s;
  }
}

// ================= single-pass softmax aggregate (edges) =============================
// out[node] = elu( (sum_e w_e * M[src_e]) / (sum_e w_e + 1e-16) + bias ),
// w_e = exp(leaky(ls[src]+ld[node]))
__global__ __launch_bounds__(256)
void agg_edges(const int* __restrict__ off, const int* __restrict__ ssrc,
               const float* __restrict__ ls, const float* __restrict__ ld,
               const float* __restrict__ Mrows, const float* __restrict__ bias,
               float* __restrict__ out, int n)
{
  int node = (int)((blockIdx.x * blockDim.x + threadIdx.x) >> 6);
  int lane = (int)(threadIdx.x & 63);
  if (node >= n) return;
  int e0 = off[node], e1 = off[node+1];
  float ldv = ld[node];
  float denom = 0.f;
  float2 acc = make_float2(0.f,0.f);
  for (int j0=e0; j0<e1; j0+=64){
    int cnt = min(64, e1-j0);
    int sc = 0; float w = 0.f;
    if (lane < cnt){
      sc = ssrc[j0+lane];
      w = expf(leakyf(ls[sc]+ldv));
    }
    denom += w;
    for (int k=0;k<cnt;k++){
      float wk = __shfl(w, k);
      int  sck = __shfl(sc, k);
      float2 m = ((const float2*)(Mrows + (size_t)sck*HID))[lane];
      acc.x += wk*m.x; acc.y += wk*m.y;
    }
  }
  for (int off_=32; off_; off_>>=1) denom += __shfl_xor(denom, off_);
  float inv = 1.f/(denom + 1e-16f);
  float2 b = ((const float2*)bias)[lane];
  ((float2*)(out + (size_t)node*HID))[lane] =
      make_float2(eluf(acc.x*inv + b.x), eluf(acc.y*inv + b.y));
}

// ================= GRU combine + relu (float4, in-place capable) =====================
__global__ __launch_bounds__(256)
void gru_combine(const float* __restrict__ gi, const float* __restrict__ gh,
                 const float* __restrict__ h, float* __restrict__ out, int rows)
{
  int i = (int)(blockIdx.x*blockDim.x + threadIdx.x);
  if (i >= rows*32) return;
  int r = i >> 5, c = (i & 31) << 2;
  const float* gir = gi + (size_t)r*384;
  const float* ghr = gh + (size_t)r*384;
  float4 gr = *(const float4*)(gir + c);
  float4 gz = *(const float4*)(gir + c + 128);
  float4 gn = *(const float4*)(gir + c + 256);
  float4 hr = *(const float4*)(ghr + c);
  float4 hz = *(const float4*)(ghr + c + 128);
  float4 hn = *(const float4*)(ghr + c + 256);
  float4 hv = *(const float4*)(h + (size_t)r*HID + c);
  float4 o;
  {
    float rr = sigmf(gr.x+hr.x), zz = sigmf(gz.x+hz.x);
    float nn = tanhf(gn.x + rr*hn.x);
    o.x = fmaxf((1.f-zz)*nn + zz*hv.x, 0.f);
  }
  {
    float rr = sigmf(gr.y+hr.y), zz = sigmf(gz.y+hz.y);
    float nn = tanhf(gn.y + rr*hn.y);
    o.y = fmaxf((1.f-zz)*nn + zz*hv.y, 0.f);
  }
  {
    float rr = sigmf(gr.z+hr.z), zz = sigmf(gz.z+hz.z);
    float nn = tanhf(gn.z + rr*hn.z);
    o.z = fmaxf((1.f-zz)*nn + zz*hv.z, 0.f);
  }
  {
    float rr = sigmf(gr.w+hr.w), zz = sigmf(gz.w+hz.w);
    float nn = tanhf(gn.w + rr*hn.w);
    o.w = fmaxf((1.f-zz)*nn + zz*hv.w, 0.f);
  }
  *(float4*)(out + (size_t)r*HID + c) = o;
}

// ================= readout kernels ===================================================
__global__ __launch_bounds__(256)
void graph_sum(const int* __restrict__ goff, const float* __restrict__ X,
               float* __restrict__ out)
{
  int g = (int)((blockIdx.x*blockDim.x + threadIdx.x) >> 6);
  int lane = (int)(threadIdx.x & 63);
  if (g >= NG) return;
  float2 acc = make_float2(0.f,0.f);
  for (int n=goff[g]; n<goff[g+1]; ++n){
    float2 v = ((const float2*)(X + (size_t)n*HID))[lane];
    acc.x += v.x; acc.y += v.y;
  }
  ((float2*)(out + (size_t)g*HID))[lane] = make_float2(fmaxf(acc.x,0.f), fmaxf(acc.y,0.f));
}

// single-pass softmax aggregate over a graph's contiguous node range
__global__ __launch_bounds__(256)
void graph_soft(const int* __restrict__ goff, const float* __restrict__ asrc,
                const float* __restrict__ adst, const float* __restrict__ Xt,
                const float* __restrict__ bias, float* __restrict__ out)
{
  int g = (int)((blockIdx.x*blockDim.x + threadIdx.x) >> 6);
  int lane = (int)(threadIdx.x & 63);
  if (g >= NG) return;
  int n0 = goff[g], n1 = goff[g+1];
  float ad = adst[g];
  float denom = 0.f;
  float2 acc = make_float2(0.f,0.f);
  for (int j0=n0; j0<n1; j0+=64){
    int cnt = min(64, n1-j0);
    float w = 0.f;
    if (lane < cnt) w = expf(leakyf(asrc[j0+lane]+ad));
    denom += w;
    for (int k=0;k<cnt;k++){
      float wk = __shfl(w, k);
      float2 v = ((const float2*)(Xt + (size_t)(j0+k)*HID))[lane];
      acc.x += wk*v.x; acc.y += wk*v.y;
    }
  }
  for (int off_=32; off_; off_>>=1) denom += __shfl_xor(denom, off_);
  float inv = 1.f/(denom + 1e-16f);
  float2 b = ((const float2*)bias)[lane];
  ((float2*)(out + (size_t)g*HID))[lane] =
      make_float2(eluf(acc.x*inv + b.x), eluf(acc.y*inv + b.y));
}

// =====================================================================================
extern "C" void kernel_launch(void* const* d_in, const int* in_sizes, int n_in,
                              void* d_out, int out_size, void* d_ws, size_t ws_size,
                              hipStream_t stream)
{
  const float* x_in  = (const float*)d_in[0];
  const int*   ei    = (const int*)d_in[1];
  const int*   batch = (const int*)d_in[2];
  const float* W1    = (const float*)d_in[3];
  const float* b1    = (const float*)d_in[4];
  const float* Wg1   = (const float*)d_in[5];
  const float* att_l = (const float*)d_in[6];
  const float* att_r = (const float*)d_in[7];
  const float* Wg2   = (const float*)d_in[8];
  const float* bg    = (const float*)d_in[9];
  const float* Wih0  = (const float*)d_in[10];
  const float* Whh0  = (const float*)d_in[11];
  const float* bih0  = (const float*)d_in[12];
  const float* bhh0  = (const float*)d_in[13];
  const float* Wa    = (const float*)d_in[14];
  const float* att_src_a = (const float*)d_in[15];
  const float* att_dst_a = (const float*)d_in[16];
  const float* ba    = (const float*)d_in[17];
  const float* Wih_a = (const float*)d_in[18];
  const float* Whh_a = (const float*)d_in[19];
  const float* bih_a = (const float*)d_in[20];
  const float* bhh_a = (const float*)d_in[21];
  const float* Wm    = (const float*)d_in[22];
  const float* att_src_m = (const float*)d_in[23];
  const float* att_dst_m = (const float*)d_in[24];
  const float* bm    = (const float*)d_in[25];
  const float* Wih_m = (const float*)d_in[26];
  const float* Whh_m = (const float*)d_in[27];
  const float* bih_m = (const float*)d_in[28];
  const float* bhh_m = (const float*)d_in[29];
  const float* W2    = (const float*)d_in[30];
  const float* b2    = (const float*)d_in[31];
  (void)in_sizes; (void)n_in; (void)out_size; (void)ws_size;

  char* wsb = (char*)d_ws;
  size_t off = 0;
  auto alloc = [&](size_t bytes)->void* {
    void* p = wsb + off;
    off += (bytes + 255) & ~(size_t)255;
    return p;
  };
  const int CH = 25000;
  float* f_x   = (float*)alloc((size_t)NN*HID*4);
  float* f_h   = (float*)alloc((size_t)NN*HID*4);
  float* f_t   = (float*)alloc((size_t)NN*HID*4);
  float* f_s1  = (float*)alloc((size_t)NN*4);
  float* f_s2  = (float*)alloc((size_t)NN*4);
  float* f_gi  = (float*)alloc((size_t)CH*384*4);
  float* f_gh  = (float*)alloc((size_t)CH*384*4);
  float* g_out = (float*)alloc((size_t)NG*HID*4);
  float* g_h   = (float*)alloc((size_t)NG*HID*4);
  float* g_adst= (float*)alloc((size_t)NG*4);
  float* g_gi  = (float*)alloc((size_t)NG*384*4);
  float* g_gh  = (float*)alloc((size_t)NG*384*4);
  float* w_g1p = (float*)alloc((size_t)HID*HID*4);
  float* w_cg  = (float*)alloc((size_t)HID*4);
  float* w_vmd = (float*)alloc((size_t)HID*4);
  int* i_cnt   = (int*)alloc((size_t)NN*4);
  int* i_off   = (int*)alloc((size_t)(NN+1)*4);
  int* i_fill  = (int*)alloc((size_t)NN*4);
  int* i_src   = (int*)alloc((size_t)NE*4);
  int* i_tot   = (int*)alloc((size_t)64*4);
  int* i_goff  = (int*)alloc((size_t)(NG+1)*4);

  const int* e_src = ei;
  const int* e_dst = ei + NE;

  hipMemsetAsync(i_cnt, 0, (size_t)NN*4, stream);
  hipMemsetAsync(i_fill, 0, (size_t)NN*4, stream);

  // CSR over dst (count -> hierarchical scan -> fill); graph offsets via binary search
  const int NB = (NN + 1023)/1024;  // 49
  count_kernel<<<(NE+255)/256,256,0,stream>>>(e_dst, i_cnt, NE);
  scan_blocks<<<NB,1024,0,stream>>>(i_cnt, i_off, i_tot, NN);
  scan_tot<<<1,64,0,stream>>>(i_tot, i_off+NN, NB);
  scan_add<<<(NN+255)/256,256,0,stream>>>(i_off, i_tot, NN);
  fill_kernel<<<(NE+255)/256,256,0,stream>>>(e_src, e_dst, i_off, i_fill, i_src, NE);
  graph_bounds<<<(NG+1+255)/256,256,0,stream>>>(batch, i_goff);
  prep_gate<<<128,128,0,stream>>>(Wg1, w_g1p, w_cg);
  colvec<<<1,128,0,stream>>>(Wm, att_dst_m, w_vmd);   // vmd = Wm^T att_dst_m

  const int RB = (NN+127)/128;               // 391 row blocks (128-tile)
  const int CB = (CH+127)/128;               // 196
  const int wavegrid_n = (NN*64+255)/256;
  const int wavegrid_g = (NG*64)/256;

  // x = leaky(x @ W1.T + b1)
  gemm_big<64><<<dim3(1,RB),256,0,stream>>>(x_in, W1, b1, f_x, NN, HID, 1);

  // ---- GATEConv ----
  gemm_big<128><<<dim3(1,RB),256,0,stream>>>(f_x, w_g1p, w_cg, f_t, NN, HID, 1);   // xe
  rowdot2<<<wavegrid_n,256,0,stream>>>(f_t, att_l, f_x, att_r, f_s1, f_s2, NN);
  gemm_big<128><<<dim3(1,RB),256,0,stream>>>(f_x, Wg2, nullptr, f_t, NN, HID, 0);  // xg2
  agg_edges<<<(NN+3)/4,256,0,stream>>>(i_off, i_src, f_s1, f_s2, f_t, bg, f_h, NN);
  for (int c0=0;c0<NN;c0+=CH){
    gemm_big<128><<<dim3(3,CB),256,0,stream>>>(f_h + (size_t)c0*HID, Wih0, bih0, f_gi, CH, 384, 0);
    gemm_big<128><<<dim3(3,CB),256,0,stream>>>(f_x + (size_t)c0*HID, Whh0, bhh0, f_gh, CH, 384, 0);
    gru_combine<<<(CH*32+255)/256,256,0,stream>>>(f_gi, f_gh, f_x+(size_t)c0*HID, f_x+(size_t)c0*HID, CH);
  }

  // ---- 2x GATConv + GRU ----
  for (int l=0;l<2;l++){
    gemm_big<128><<<dim3(1,RB),256,0,stream>>>(f_x, Wa + (size_t)l*HID*HID, nullptr, f_t, NN, HID, 0);
    rowdot2<<<wavegrid_n,256,0,stream>>>(f_t, att_src_a + l*HID, f_t, att_dst_a + l*HID, f_s1, f_s2, NN);
    agg_edges<<<(NN+3)/4,256,0,stream>>>(i_off, i_src, f_s1, f_s2, f_t, ba + l*HID, f_h, NN);
    for (int c0=0;c0<NN;c0+=CH){
      gemm_big<128><<<dim3(3,CB),256,0,stream>>>(f_h + (size_t)c0*HID, Wih_a + (size_t)l*384*HID, bih_a + l*384, f_gi, CH, 384, 0);
      gemm_big<128><<<dim3(3,CB),256,0,stream>>>(f_x + (size_t)c0*HID, Whh_a + (size_t)l*384*HID, bhh_a + l*384, f_gh, CH, 384, 0);
      gru_combine<<<(CH*32+255)/256,256,0,stream>>>(f_gi, f_gh, f_x+(size_t)c0*HID, f_x+(size_t)c0*HID, CH);
    }
  }

  // ---- attentive readout ----
  graph_sum<<<wavegrid_g,256,0,stream>>>(i_goff, f_x, g_out);
  gemm_big<128><<<dim3(1,RB),256,0,stream>>>(f_x, Wm, nullptr, f_t, NN, HID, 0);   // xt
  rowdot<<<wavegrid_n,256,0,stream>>>(f_t, att_src_m, nullptr, f_s1, NN);          // a_src
  for (int t=0;t<3;t++){
    // a_dst[g] = (out @ Wm^T) . att_dst_m = out . vmd
    rowdot<<<wavegrid_g,256,0,stream>>>(g_out, w_vmd, nullptr, g_adst, NG);
    graph_soft<<<wavegrid_g,256,0,stream>>>(i_goff, f_s1, g_adst, f_t, bm, g_h);
    gemm_nt<128><<<dim3(6,(NG+63)/64),256,0,stream>>>(g_h, Wih_m, bih_m, g_gi, NG, 384, 0);
    gemm_nt<128><<<dim3(6,(NG+63)/64),256,0,stream>>>(g_out, Whh_m, bhh_m, g_gh, NG, 384, 0);
    gru_combine<<<(NG*32+255)/256,256,0,stream>>>(g_gi, g_gh, g_out, g_out, NG);
  }

  rowdot<<<wavegrid_g,256,0,stream>>>(g_out, W2, b2, (float*)d_out, NG);
}

// Round 3
// 1238.487 us; speedup vs baseline: 1.4459x; 1.1031x over previous
//
#include <hip/hip_runtime.h>
#include <math.h>

#define NN 50000
#define NE 800000
#define NG 1024
#define HID 128

typedef __attribute__((ext_vector_type(8))) short short8;
typedef __attribute__((ext_vector_type(4))) unsigned short ushort4v;
typedef __attribute__((ext_vector_type(4))) float f32x4;

__device__ __forceinline__ float leakyf(float v){ return v >= 0.f ? v : 0.01f*v; }
__device__ __forceinline__ float sigmf(float v){ return 1.f/(1.f+expf(-v)); }
__device__ __forceinline__ float eluf(float v){ return v > 0.f ? v : expm1f(v); }
__device__ __forceinline__ unsigned short bf16rne(float f){
  union { float f; unsigned u; } v; v.f = f;
  return (unsigned short)((v.u + 0x7FFFu + ((v.u >> 16) & 1u)) >> 16);
}
__device__ __forceinline__ float bf2f(unsigned short h){
  union { unsigned u; float f; } v; v.u = ((unsigned)h) << 16; return v.f;
}

// ================= bf16-MFMA GEMM, fp32 in/out =======================================
// C[r,m] = act(sum_k A[r,k]*W[m,k] + bias[m]); A rows x K fp32, W M x K fp32.
// Staging converts to bf16 in LDS; MFMA 16x16x32 accumulates fp32.
// grid = (M/128, ceil(rows/128)), block = 256 (4 waves, each 64x64 of the 128x128 tile)
template<int K>
__global__ __launch_bounds__(256)
void gemm_mfma(const float* __restrict__ A, const float* __restrict__ W,
               const float* __restrict__ bias, float* __restrict__ Cf,
               unsigned short* __restrict__ Cb, int rows, int M, int act)
{
  constexpr int STR = K + 8;      // bf16 elems per LDS row (pad 16B to spread banks)
  __shared__ __align__(16) unsigned short As[128*STR];
  __shared__ __align__(16) unsigned short Ws[128*STR];
  const int tid = (int)threadIdx.x;
  const int bm = blockIdx.x * 128;
  const int bn = blockIdx.y * 128;

  // ---- stage A,W tiles (fp32 -> bf16) ----
  constexpr int F4PT = (128*K/4)/256;
#pragma unroll
  for (int i=0;i<F4PT;i++){
    int f = i*256 + tid;
    int row = f/(K/4), kp = (f%(K/4))*4;
    float4 av = make_float4(0,0,0,0);
    int ar = bn + row;
    if (ar < rows) av = *(const float4*)(A + (size_t)ar*K + kp);
    ushort4v ua; ua.x=bf16rne(av.x); ua.y=bf16rne(av.y); ua.z=bf16rne(av.z); ua.w=bf16rne(av.w);
    *(ushort4v*)&As[row*STR + kp] = ua;
    float4 wv = *(const float4*)(W + (size_t)(bm+row)*K + kp);
    ushort4v uw; uw.x=bf16rne(wv.x); uw.y=bf16rne(wv.y); uw.z=bf16rne(wv.z); uw.w=bf16rne(wv.w);
    *(ushort4v*)&Ws[row*STR + kp] = uw;
  }
  __syncthreads();

  // ---- MFMA ----
  const int w = tid >> 6, l = tid & 63;
  const int wr = (w >> 1)*64, wc = (w & 1)*64;
  const int fr = l & 15, fq = l >> 4;
  f32x4 acc[4][4];
#pragma unroll
  for (int i=0;i<4;i++)
#pragma unroll
    for (int j=0;j<4;j++) acc[i][j] = (f32x4){0.f,0.f,0.f,0.f};
#pragma unroll
  for (int s=0;s<K/32;s++){
    short8 af[4], bfv[4];
#pragma unroll
    for (int i=0;i<4;i++) af[i]  = *(const short8*)&As[(wr+i*16+fr)*STR + s*32 + fq*8];
#pragma unroll
    for (int j=0;j<4;j++) bfv[j] = *(const short8*)&Ws[(wc+j*16+fr)*STR + s*32 + fq*8];
#pragma unroll
    for (int i=0;i<4;i++)
#pragma unroll
      for (int j=0;j<4;j++)
        acc[i][j] = __builtin_amdgcn_mfma_f32_16x16x32_bf16(af[i], bfv[j], acc[i][j], 0, 0, 0);
  }

  // ---- epilogue: C/D layout col=lane&15, row=(lane>>4)*4+reg ----
#pragma unroll
  for (int j=0;j<4;j++){
    int c = bm + wc + j*16 + fr;
    float bv = bias ? bias[c] : 0.f;
#pragma unroll
    for (int i=0;i<4;i++){
#pragma unroll
      for (int r4=0;r4<4;r4++){
        int r = bn + wr + i*16 + fq*4 + r4;
        if (r < rows){
          float v = acc[i][j][r4] + bv;
          if (act) v = leakyf(v);
          if (Cf) Cf[(size_t)r*M + c] = v;
          if (Cb) Cb[(size_t)r*M + c] = bf16rne(v);
        }
      }
    }
  }
}

// ================= small fp32 GEMM (64x64 tile) for graph-level (rows=1024) ==========
template<int K>
__global__ __launch_bounds__(256)
void gemm_nt(const float* __restrict__ A, const float* __restrict__ W,
             const float* __restrict__ bias, float* __restrict__ C,
             int rows, int M, int act)
{
  __shared__ float As[16][68];
  __shared__ float Ws[16][68];
  const int bm = blockIdx.x * 64;
  const int bn = blockIdx.y * 64;
  const int tid = (int)threadIdx.x;
  const int tx = tid & 15, ty = tid >> 4;
  const int lrow = tid >> 2;
  const int lk   = (tid & 3) << 2;
  const int arow = bn + lrow;
  float acc[4][4] = {};
  for (int k0 = 0; k0 < K; k0 += 16) {
    float4 av = make_float4(0,0,0,0);
    if (arow < rows) av = *(const float4*)(A + (size_t)arow*K + k0 + lk);
    float4 wv = *(const float4*)(W + (size_t)(bm+lrow)*K + k0 + lk);
    __syncthreads();
    As[lk+0][lrow]=av.x; As[lk+1][lrow]=av.y; As[lk+2][lrow]=av.z; As[lk+3][lrow]=av.w;
    Ws[lk+0][lrow]=wv.x; Ws[lk+1][lrow]=wv.y; Ws[lk+2][lrow]=wv.z; Ws[lk+3][lrow]=wv.w;
    __syncthreads();
#pragma unroll
    for (int kk = 0; kk < 16; ++kk) {
      float4 a = *(const float4*)&As[kk][ty<<2];
      float4 b = *(const float4*)&Ws[kk][tx<<2];
      float av_[4]={a.x,a.y,a.z,a.w}, bv_[4]={b.x,b.y,b.z,b.w};
#pragma unroll
      for(int i=0;i<4;i++)
#pragma unroll
        for(int j=0;j<4;j++) acc[i][j]+=av_[i]*bv_[j];
    }
  }
  float4 bv = make_float4(0,0,0,0);
  if (bias) bv = *(const float4*)(bias + bm + (tx<<2));
#pragma unroll
  for (int i=0;i<4;i++){
    int r = bn + (ty<<2) + i;
    if (r < rows) {
      float4 o;
      o.x = acc[i][0]+bv.x; o.y = acc[i][1]+bv.y; o.z = acc[i][2]+bv.z; o.w = acc[i][3]+bv.w;
      if (act==1){ o.x=leakyf(o.x); o.y=leakyf(o.y); o.z=leakyf(o.z); o.w=leakyf(o.w); }
      *(float4*)(C + (size_t)r*M + bm + (tx<<2)) = o;
    }
  }
}

// ================= rowdots ===========================================================
__global__ __launch_bounds__(256)
void rowdot(const float* __restrict__ A, const float* __restrict__ v,
            const float* __restrict__ bias, float* __restrict__ out, int rows)
{
  int wave = (int)((blockIdx.x * blockDim.x + threadIdx.x) >> 6);
  int lane = (int)(threadIdx.x & 63);
  if (wave >= rows) return;
  float2 a  = ((const float2*)(A + (size_t)wave*HID))[lane];
  float2 vv = ((const float2*)v)[lane];
  float s = a.x*vv.x + a.y*vv.y;
  for (int off=32; off; off>>=1) s += __shfl_down(s, off);
  if (lane==0) out[wave] = s + (bias ? bias[0] : 0.f);
}

// A is bf16 rows x 128
__global__ __launch_bounds__(256)
void rowdot_b(const unsigned short* __restrict__ A, const float* __restrict__ v,
              float* __restrict__ out, int rows)
{
  int wave = (int)((blockIdx.x * blockDim.x + threadIdx.x) >> 6);
  int lane = (int)(threadIdx.x & 63);
  if (wave >= rows) return;
  unsigned aa = *(const unsigned*)(A + (size_t)wave*HID + lane*2);
  float2 vv = ((const float2*)v)[lane];
  float s = bf2f((unsigned short)(aa&0xffff))*vv.x + bf2f((unsigned short)(aa>>16))*vv.y;
  for (int off=32; off; off>>=1) s += __shfl_down(s, off);
  if (lane==0) out[wave] = s;
}

// both dots read the same bf16 row
__global__ __launch_bounds__(256)
void rowdot2_b(const unsigned short* __restrict__ A, const float* __restrict__ v1,
               const float* __restrict__ v2, float* __restrict__ o1,
               float* __restrict__ o2, int rows)
{
  int wave = (int)((blockIdx.x * blockDim.x + threadIdx.x) >> 6);
  int lane = (int)(threadIdx.x & 63);
  if (wave >= rows) return;
  unsigned aa = *(const unsigned*)(A + (size_t)wave*HID + lane*2);
  float ax = bf2f((unsigned short)(aa&0xffff)), ay = bf2f((unsigned short)(aa>>16));
  float2 w1 = ((const float2*)v1)[lane];
  float2 w2 = ((const float2*)v2)[lane];
  float s1 = ax*w1.x + ay*w1.y;
  float s2 = ax*w2.x + ay*w2.y;
  for (int off=32; off; off>>=1){ s1 += __shfl_down(s1, off); s2 += __shfl_down(s2, off); }
  if (lane==0){ o1[wave]=s1; o2[wave]=s2; }
}

// out[k] = sum_j W[j,k]*v[j]   (W: 128x128)
__global__ void colvec(const float* __restrict__ W, const float* __restrict__ v,
                       float* __restrict__ out)
{
  int k = (int)threadIdx.x;
  float s = 0.f;
  for (int j=0;j<HID;j++) s += W[j*HID+k]*v[j];
  out[k] = s;
}

// ================= CSR build (grid-parallel scan) ====================================
__global__ void count_kernel(const int* __restrict__ idx, int* __restrict__ cnt, int n){
  int i = (int)(blockIdx.x*blockDim.x + threadIdx.x);
  if (i < n) atomicAdd(&cnt[idx[i]], 1);
}

__global__ __launch_bounds__(1024)
void scan_blocks(const int* __restrict__ cnt, int* __restrict__ off,
                 int* __restrict__ tot, int n)
{
  __shared__ int buf[1024];
  int i = (int)(blockIdx.x*1024 + threadIdx.x);
  int v = (i<n)? cnt[i] : 0;
  buf[threadIdx.x] = v;
  __syncthreads();
  for (int s=1;s<1024;s<<=1){
    int t = ((int)threadIdx.x >= s) ? buf[threadIdx.x - s] : 0;
    __syncthreads();
    buf[threadIdx.x] += t;
    __syncthreads();
  }
  if (i<n) off[i] = buf[threadIdx.x] - v;
  if (threadIdx.x==1023) tot[blockIdx.x] = buf[1023];
}

__global__ void scan_tot(int* __restrict__ tot, int* __restrict__ off_end, int nb){
  int lane = (int)threadIdx.x;
  int orig = (lane<nb)? tot[lane] : 0;
  int v = orig;
  for (int s=1;s<64;s<<=1){ int t = __shfl_up(v, s); if (lane>=s) v += t; }
  int total = __shfl(v, 63);
  if (lane<nb) tot[lane] = v - orig;
  if (lane==0) *off_end = total;
}

__global__ void scan_add(int* __restrict__ off, const int* __restrict__ tot, int n){
  int i = (int)(blockIdx.x*blockDim.x + threadIdx.x);
  if (i<n) off[i] += tot[i>>10];
}

__global__ void fill_kernel(const int* __restrict__ src, const int* __restrict__ dst,
                            const int* __restrict__ off, int* __restrict__ fill,
                            int* __restrict__ ssrc, int n){
  int e = (int)(blockIdx.x*blockDim.x + threadIdx.x);
  if (e < n){
    int d = dst[e];
    int p = off[d] + atomicAdd(&fill[d], 1);
    ssrc[p] = src[e];
  }
}

__global__ void graph_bounds(const int* __restrict__ batch, int* __restrict__ goff){
  int g = (int)(blockIdx.x*blockDim.x + threadIdx.x);
  if (g > NG) return;
  int lo=0, hi=NN;
  while (lo<hi){ int mid=(lo+hi)>>1; if (batch[mid] < g) lo=mid+1; else hi=mid; }
  goff[g] = lo;
}

// ================= pack Wg1[:, :128] and cg = rowsum(Wg1[:,128:153]) =================
__global__ void prep_gate(const float* __restrict__ Wg1, float* __restrict__ Wp,
                          float* __restrict__ cg){
  int j = (int)blockIdx.x;
  int t = (int)threadIdx.x;
  Wp[j*128 + t] = Wg1[j*153 + t];
  if (t == 0){
    float s = 0.f;
    for (int k=128;k<153;k++) s += Wg1[j*153+k];
    cg[j] = s;
  }
}

// ================= single-pass softmax aggregate (edges), bf16 message rows ==========
__global__ __launch_bounds__(256)
void agg_edges(const int* __restrict__ off, const int* __restrict__ ssrc,
               const float* __restrict__ ls, const float* __restrict__ ld,
               const unsigned short* __restrict__ Mrows, const float* __restrict__ bias,
               float* __restrict__ out, int n)
{
  int node = (int)((blockIdx.x * blockDim.x + threadIdx.x) >> 6);
  int lane = (int)(threadIdx.x & 63);
  if (node >= n) return;
  int e0 = off[node], e1 = off[node+1];
  float ldv = ld[node];
  float denom = 0.f;
  float2 acc = make_float2(0.f,0.f);
  for (int j0=e0; j0<e1; j0+=64){
    int cnt = min(64, e1-j0);
    int sc = 0; float wv = 0.f;
    if (lane < cnt){
      sc = ssrc[j0+lane];
      wv = expf(leakyf(ls[sc]+ldv));
    }
    denom += wv;
    for (int k=0;k<cnt;k++){
      float wk = __shfl(wv, k);
      int  sck = __shfl(sc, k);
      unsigned mm = *(const unsigned*)(Mrows + (size_t)sck*HID + lane*2);
      acc.x += wk*bf2f((unsigned short)(mm&0xffff));
      acc.y += wk*bf2f((unsigned short)(mm>>16));
    }
  }
  for (int off_=32; off_; off_>>=1) denom += __shfl_xor(denom, off_);
  float inv = 1.f/(denom + 1e-16f);
  float2 b = ((const float2*)bias)[lane];
  ((float2*)(out + (size_t)node*HID))[lane] =
      make_float2(eluf(acc.x*inv + b.x), eluf(acc.y*inv + b.y));
}

// ================= GRU combine + relu ================================================
__global__ __launch_bounds__(256)
void gru_combine(const float* __restrict__ gi, const float* __restrict__ gh,
                 const float* __restrict__ h, float* __restrict__ out, int rows)
{
  int i = (int)(blockIdx.x*blockDim.x + threadIdx.x);
  if (i >= rows*32) return;
  int r = i >> 5, c = (i & 31) << 2;
  const float* gir = gi + (size_t)r*384;
  const float* ghr = gh + (size_t)r*384;
  float4 gr = *(const float4*)(gir + c);
  float4 gz = *(const float4*)(gir + c + 128);
  float4 gn = *(const float4*)(gir + c + 256);
  float4 hr = *(const float4*)(ghr + c);
  float4 hz = *(const float4*)(ghr + c + 128);
  float4 hn = *(const float4*)(ghr + c + 256);
  float4 hv = *(const float4*)(h + (size_t)r*HID + c);
  float4 o;
  { float rr=sigmf(gr.x+hr.x), zz=sigmf(gz.x+hz.x); float nn=tanhf(gn.x+rr*hn.x); o.x=fmaxf((1.f-zz)*nn+zz*hv.x,0.f); }
  { float rr=sigmf(gr.y+hr.y), zz=sigmf(gz.y+hz.y); float nn=tanhf(gn.y+rr*hn.y); o.y=fmaxf((1.f-zz)*nn+zz*hv.y,0.f); }
  { float rr=sigmf(gr.z+hr.z), zz=sigmf(gz.z+hz.z); float nn=tanhf(gn.z+rr*hn.z); o.z=fmaxf((1.f-zz)*nn+zz*hv.z,0.f); }
  { float rr=sigmf(gr.w+hr.w), zz=sigmf(gz.w+hz.w); float nn=tanhf(gn.w+rr*hn.w); o.w=fmaxf((1.f-zz)*nn+zz*hv.w,0.f); }
  *(float4*)(out + (size_t)r*HID + c) = o;
}

// ================= readout kernels ===================================================
__global__ __launch_bounds__(256)
void graph_sum(const int* __restrict__ goff, const float* __restrict__ X,
               float* __restrict__ out)
{
  int g = (int)((blockIdx.x*blockDim.x + threadIdx.x) >> 6);
  int lane = (int)(threadIdx.x & 63);
  if (g >= NG) return;
  float2 acc = make_float2(0.f,0.f);
  for (int n=goff[g]; n<goff[g+1]; ++n){
    float2 v = ((const float2*)(X + (size_t)n*HID))[lane];
    acc.x += v.x; acc.y += v.y;
  }
  ((float2*)(out + (size_t)g*HID))[lane] = make_float2(fmaxf(acc.x,0.f), fmaxf(acc.y,0.f));
}

// single-pass softmax aggregate over a graph's contiguous node range, bf16 Xt
__global__ __launch_bounds__(256)
void graph_soft(const int* __restrict__ goff, const float* __restrict__ asrc,
                const float* __restrict__ adst, const unsigned short* __restrict__ Xt,
                const float* __restrict__ bias, float* __restrict__ out)
{
  int g = (int)((blockIdx.x*blockDim.x + threadIdx.x) >> 6);
  int lane = (int)(threadIdx.x & 63);
  if (g >= NG) return;
  int n0 = goff[g], n1 = goff[g+1];
  float ad = adst[g];
  float denom = 0.f;
  float2 acc = make_float2(0.f,0.f);
  for (int j0=n0; j0<n1; j0+=64){
    int cnt = min(64, n1-j0);
    float wv = 0.f;
    if (lane < cnt) wv = expf(leakyf(asrc[j0+lane]+ad));
    denom += wv;
    for (int k=0;k<cnt;k++){
      float wk = __shfl(wv, k);
      unsigned mm = *(const unsigned*)(Xt + (size_t)(j0+k)*HID + lane*2);
      acc.x += wk*bf2f((unsigned short)(mm&0xffff));
      acc.y += wk*bf2f((unsigned short)(mm>>16));
    }
  }
  for (int off_=32; off_; off_>>=1) denom += __shfl_xor(denom, off_);
  float inv = 1.f/(denom + 1e-16f);
  float2 b = ((const float2*)bias)[lane];
  ((float2*)(out + (size_t)g*HID))[lane] =
      make_float2(eluf(acc.x*inv + b.x), eluf(acc.y*inv + b.y));
}

// =====================================================================================
extern "C" void kernel_launch(void* const* d_in, const int* in_sizes, int n_in,
                              void* d_out, int out_size, void* d_ws, size_t ws_size,
                              hipStream_t stream)
{
  const float* x_in  = (const float*)d_in[0];
  const int*   ei    = (const int*)d_in[1];
  const int*   batch = (const int*)d_in[2];
  const float* W1    = (const float*)d_in[3];
  const float* b1    = (const float*)d_in[4];
  const float* Wg1   = (const float*)d_in[5];
  const float* att_l = (const float*)d_in[6];
  const float* att_r = (const float*)d_in[7];
  const float* Wg2   = (const float*)d_in[8];
  const float* bg    = (const float*)d_in[9];
  const float* Wih0  = (const float*)d_in[10];
  const float* Whh0  = (const float*)d_in[11];
  const float* bih0  = (const float*)d_in[12];
  const float* bhh0  = (const float*)d_in[13];
  const float* Wa    = (const float*)d_in[14];
  const float* att_src_a = (const float*)d_in[15];
  const float* att_dst_a = (const float*)d_in[16];
  const float* ba    = (const float*)d_in[17];
  const float* Wih_a = (const float*)d_in[18];
  const float* Whh_a = (const float*)d_in[19];
  const float* bih_a = (const float*)d_in[20];
  const float* bhh_a = (const float*)d_in[21];
  const float* Wm    = (const float*)d_in[22];
  const float* att_src_m = (const float*)d_in[23];
  const float* att_dst_m = (const float*)d_in[24];
  const float* bm    = (const float*)d_in[25];
  const float* Wih_m = (const float*)d_in[26];
  const float* Whh_m = (const float*)d_in[27];
  const float* bih_m = (const float*)d_in[28];
  const float* bhh_m = (const float*)d_in[29];
  const float* W2    = (const float*)d_in[30];
  const float* b2    = (const float*)d_in[31];
  (void)in_sizes; (void)n_in; (void)out_size; (void)ws_size;

  char* wsb = (char*)d_ws;
  size_t off = 0;
  auto alloc = [&](size_t bytes)->void* {
    void* p = wsb + off;
    off += (bytes + 255) & ~(size_t)255;
    return p;
  };
  const int CH = 25000;
  float* f_x   = (float*)alloc((size_t)NN*HID*4);
  float* f_h   = (float*)alloc((size_t)NN*HID*4);
  unsigned short* f_t = (unsigned short*)alloc((size_t)NN*HID*2);   // bf16 message/attn matrix
  float* f_s1  = (float*)alloc((size_t)NN*4);
  float* f_s2  = (float*)alloc((size_t)NN*4);
  float* f_gi  = (float*)alloc((size_t)CH*384*4);
  float* f_gh  = (float*)alloc((size_t)CH*384*4);
  float* g_out = (float*)alloc((size_t)NG*HID*4);
  float* g_h   = (float*)alloc((size_t)NG*HID*4);
  float* g_adst= (float*)alloc((size_t)NG*4);
  float* g_gi  = (float*)alloc((size_t)NG*384*4);
  float* g_gh  = (float*)alloc((size_t)NG*384*4);
  float* w_g1p = (float*)alloc((size_t)HID*HID*4);
  float* w_cg  = (float*)alloc((size_t)HID*4);
  float* w_vmd = (float*)alloc((size_t)HID*4);
  int* i_cnt   = (int*)alloc((size_t)NN*4);
  int* i_off   = (int*)alloc((size_t)(NN+1)*4);
  int* i_fill  = (int*)alloc((size_t)NN*4);
  int* i_src   = (int*)alloc((size_t)NE*4);
  int* i_tot   = (int*)alloc((size_t)64*4);
  int* i_goff  = (int*)alloc((size_t)(NG+1)*4);

  const int* e_src = ei;
  const int* e_dst = ei + NE;

  hipMemsetAsync(i_cnt, 0, (size_t)NN*4, stream);
  hipMemsetAsync(i_fill, 0, (size_t)NN*4, stream);

  const int NB = (NN + 1023)/1024;
  count_kernel<<<(NE+255)/256,256,0,stream>>>(e_dst, i_cnt, NE);
  scan_blocks<<<NB,1024,0,stream>>>(i_cnt, i_off, i_tot, NN);
  scan_tot<<<1,64,0,stream>>>(i_tot, i_off+NN, NB);
  scan_add<<<(NN+255)/256,256,0,stream>>>(i_off, i_tot, NN);
  fill_kernel<<<(NE+255)/256,256,0,stream>>>(e_src, e_dst, i_off, i_fill, i_src, NE);
  graph_bounds<<<(NG+1+255)/256,256,0,stream>>>(batch, i_goff);
  prep_gate<<<128,128,0,stream>>>(Wg1, w_g1p, w_cg);
  colvec<<<1,128,0,stream>>>(Wm, att_dst_m, w_vmd);

  const int RB = (NN+127)/128;
  const int CB = (CH+127)/128;
  const int wavegrid_n = (NN*64+255)/256;
  const int wavegrid_g = (NG*64)/256;

  // x = leaky(x @ W1.T + b1)  (fp32 out)
  gemm_mfma<64><<<dim3(1,RB),256,0,stream>>>(x_in, W1, b1, f_x, nullptr, NN, HID, 1);

  // ---- GATEConv ----
  gemm_mfma<128><<<dim3(1,RB),256,0,stream>>>(f_x, w_g1p, w_cg, nullptr, f_t, NN, HID, 1); // xe (bf16)
  rowdot_b<<<wavegrid_n,256,0,stream>>>(f_t, att_l, f_s1, NN);
  rowdot  <<<wavegrid_n,256,0,stream>>>(f_x, att_r, nullptr, f_s2, NN);
  gemm_mfma<128><<<dim3(1,RB),256,0,stream>>>(f_x, Wg2, nullptr, nullptr, f_t, NN, HID, 0); // xg2 (bf16)
  agg_edges<<<(NN+3)/4,256,0,stream>>>(i_off, i_src, f_s1, f_s2, f_t, bg, f_h, NN);
  for (int c0=0;c0<NN;c0+=CH){
    gemm_mfma<128><<<dim3(3,CB),256,0,stream>>>(f_h + (size_t)c0*HID, Wih0, bih0, f_gi, nullptr, CH, 384, 0);
    gemm_mfma<128><<<dim3(3,CB),256,0,stream>>>(f_x + (size_t)c0*HID, Whh0, bhh0, f_gh, nullptr, CH, 384, 0);
    gru_combine<<<(CH*32+255)/256,256,0,stream>>>(f_gi, f_gh, f_x+(size_t)c0*HID, f_x+(size_t)c0*HID, CH);
  }

  // ---- 2x GATConv + GRU ----
  for (int l=0;l<2;l++){
    gemm_mfma<128><<<dim3(1,RB),256,0,stream>>>(f_x, Wa + (size_t)l*HID*HID, nullptr, nullptr, f_t, NN, HID, 0);
    rowdot2_b<<<wavegrid_n,256,0,stream>>>(f_t, att_src_a + l*HID, att_dst_a + l*HID, f_s1, f_s2, NN);
    agg_edges<<<(NN+3)/4,256,0,stream>>>(i_off, i_src, f_s1, f_s2, f_t, ba + l*HID, f_h, NN);
    for (int c0=0;c0<NN;c0+=CH){
      gemm_mfma<128><<<dim3(3,CB),256,0,stream>>>(f_h + (size_t)c0*HID, Wih_a + (size_t)l*384*HID, bih_a + l*384, f_gi, nullptr, CH, 384, 0);
      gemm_mfma<128><<<dim3(3,CB),256,0,stream>>>(f_x + (size_t)c0*HID, Whh_a + (size_t)l*384*HID, bhh_a + l*384, f_gh, nullptr, CH, 384, 0);
      gru_combine<<<(CH*32+255)/256,256,0,stream>>>(f_gi, f_gh, f_x+(size_t)c0*HID, f_x+(size_t)c0*HID, CH);
    }
  }

  // ---- attentive readout ----
  graph_sum<<<wavegrid_g,256,0,stream>>>(i_goff, f_x, g_out);
  gemm_mfma<128><<<dim3(1,RB),256,0,stream>>>(f_x, Wm, nullptr, nullptr, f_t, NN, HID, 0); // xt (bf16)
  rowdot_b<<<wavegrid_n,256,0,stream>>>(f_t, att_src_m, f_s1, NN);
  for (int t=0;t<3;t++){
    rowdot<<<wavegrid_g,256,0,stream>>>(g_out, w_vmd, nullptr, g_adst, NG);
    graph_soft<<<wavegrid_g,256,0,stream>>>(i_goff, f_s1, g_adst, f_t, bm, g_h);
    gemm_nt<128><<<dim3(6,(NG+63)/64),256,0,stream>>>(g_h, Wih_m, bih_m, g_gi, NG, 384, 0);
    gemm_nt<128><<<dim3(6,(NG+63)/64),256,0,stream>>>(g_out, Whh_m, bhh_m, g_gh, NG, 384, 0);
    gru_combine<<<(NG*32+255)/256,256,0,stream>>>(g_gi, g_gh, g_out, g_out, NG);
  }

  rowdot<<<wavegrid_g,256,0,stream>>>(g_out, W2, b2, (float*)d_out, NG);
}

// Round 4
// 888.268 us; speedup vs baseline: 2.0160x; 1.3943x over previous
//
#include <hip/hip_runtime.h>
#include <math.h>

#define NN 50000
#define NE 800000
#define NG 1024
#define HID 128

typedef __attribute__((ext_vector_type(8))) short short8;
typedef __attribute__((ext_vector_type(4))) unsigned short ushort4v;
typedef __attribute__((ext_vector_type(4))) float f32x4;

__device__ __forceinline__ float leakyf(float v){ return v >= 0.f ? v : 0.01f*v; }
__device__ __forceinline__ float sigmf(float v){ return 1.f/(1.f+expf(-v)); }
__device__ __forceinline__ float eluf(float v){ return v > 0.f ? v : expm1f(v); }
__device__ __forceinline__ unsigned short bf16rne(float f){
  union { float f; unsigned u; } v; v.f = f;
  return (unsigned short)((v.u + 0x7FFFu + ((v.u >> 16) & 1u)) >> 16);
}
__device__ __forceinline__ float bf2f(unsigned short h){
  union { unsigned u; float f; } v; v.u = ((unsigned)h) << 16; return v.f;
}

// ================= gemm64: 64 rows x 128 cols tile, BK=64, bf16 MFMA =================
// C[r,m] = act(sum_k A[r,k]*W[m,k] + bias[m]); A rows x K fp32, W 128 x K fp32.
// grid = (ceil(rows/64)), block = 256. LDS 27.6 KB -> 5 blocks/CU.
template<int K>
__global__ __launch_bounds__(256)
void gemm64(const float* __restrict__ A, const float* __restrict__ W,
            const float* __restrict__ bias, float* __restrict__ Cf,
            unsigned short* __restrict__ Cb, int rows, int act)
{
  __shared__ __align__(16) unsigned short As[64*72];
  __shared__ __align__(16) unsigned short Ws[128*72];
  const int tid = (int)threadIdx.x;
  const int bn = blockIdx.x * 64;
  const int w = tid >> 6, l = tid & 63;
  const int fr = l & 15, fq = l >> 4;
  const int rh = (w >> 1) * 32;   // row half base within tile
  const int ch = (w & 1) * 64;    // col half base
  f32x4 acc[2][4];
#pragma unroll
  for (int i=0;i<2;i++)
#pragma unroll
    for (int j=0;j<4;j++) acc[i][j] = (f32x4){0.f,0.f,0.f,0.f};

  for (int kb = 0; kb < K; kb += 64){
    if (kb) __syncthreads();
    // stage A: 64x64 -> 1024 float4, 4/thread
#pragma unroll
    for (int i=0;i<4;i++){
      int f = i*256 + tid;
      int row = f >> 4, kp = (f & 15) << 2;
      float4 av = make_float4(0,0,0,0);
      int ar = bn + row;
      if (ar < rows) av = *(const float4*)(A + (size_t)ar*K + kb + kp);
      ushort4v ua; ua.x=bf16rne(av.x); ua.y=bf16rne(av.y); ua.z=bf16rne(av.z); ua.w=bf16rne(av.w);
      *(ushort4v*)&As[row*72 + kp] = ua;
    }
    // stage W: 128x64 -> 2048 float4, 8/thread
#pragma unroll
    for (int i=0;i<8;i++){
      int f = i*256 + tid;
      int row = f >> 4, kp = (f & 15) << 2;
      float4 wv = *(const float4*)(W + (size_t)row*K + kb + kp);
      ushort4v uw; uw.x=bf16rne(wv.x); uw.y=bf16rne(wv.y); uw.z=bf16rne(wv.z); uw.w=bf16rne(wv.w);
      *(ushort4v*)&Ws[row*72 + kp] = uw;
    }
    __syncthreads();
#pragma unroll
    for (int s=0;s<2;s++){
      short8 af[2], bf[4];
#pragma unroll
      for (int i=0;i<2;i++) af[i] = *(const short8*)&As[(rh + i*16 + fr)*72 + s*32 + fq*8];
#pragma unroll
      for (int j=0;j<4;j++) bf[j] = *(const short8*)&Ws[(ch + j*16 + fr)*72 + s*32 + fq*8];
#pragma unroll
      for (int i=0;i<2;i++)
#pragma unroll
        for (int j=0;j<4;j++)
          acc[i][j] = __builtin_amdgcn_mfma_f32_16x16x32_bf16(af[i], bf[j], acc[i][j], 0, 0, 0);
    }
  }
  // epilogue: C/D layout col=lane&15, row=(lane>>4)*4+reg
#pragma unroll
  for (int j=0;j<4;j++){
    int c = ch + j*16 + fr;
    float bv = bias ? bias[c] : 0.f;
#pragma unroll
    for (int i=0;i<2;i++){
#pragma unroll
      for (int r4=0;r4<4;r4++){
        int r = bn + rh + i*16 + fq*4 + r4;
        if (r < rows){
          float v = acc[i][j][r4] + bv;
          if (act) v = leakyf(v);
          if (Cf) Cf[(size_t)r*HID + c] = v;
          if (Cb) Cb[(size_t)r*HID + c] = bf16rne(v);
        }
      }
    }
  }
}

// ================= fused GRU: gi=Ah@Wi^T+bih, gh=Ax@Wh^T+bhh, combine, relu ==========
// Wi/Wh are bf16 384x128 (pre-converted). out may alias Ax. 32 rows/block.
__global__ __launch_bounds__(256)
void fused_gru(const float* __restrict__ Ah, const float* __restrict__ Ax,
               const unsigned short* __restrict__ Wi, const unsigned short* __restrict__ Wh,
               const float* __restrict__ bih, const float* __restrict__ bhh,
               float* __restrict__ out, int rows)
{
  __shared__ __align__(16) unsigned short Ahs[32*136];
  __shared__ __align__(16) unsigned short Axs[32*136];
  const int tid = (int)threadIdx.x;
  const int bn = blockIdx.x * 32;
  // stage: 32x128 fp32 -> bf16, 4 float4/thread per matrix
#pragma unroll
  for (int i=0;i<4;i++){
    int f = i*256 + tid;
    int row = f >> 5, kp = (f & 31) << 2;
    int ar = bn + row;
    float4 av = make_float4(0,0,0,0), xv = make_float4(0,0,0,0);
    if (ar < rows){
      av = *(const float4*)(Ah + (size_t)ar*HID + kp);
      xv = *(const float4*)(Ax + (size_t)ar*HID + kp);
    }
    ushort4v ua; ua.x=bf16rne(av.x); ua.y=bf16rne(av.y); ua.z=bf16rne(av.z); ua.w=bf16rne(av.w);
    *(ushort4v*)&Ahs[row*136 + kp] = ua;
    ushort4v ux; ux.x=bf16rne(xv.x); ux.y=bf16rne(xv.y); ux.z=bf16rne(xv.z); ux.w=bf16rne(xv.w);
    *(ushort4v*)&Axs[row*136 + kp] = ux;
  }
  __syncthreads();

  const int w = tid >> 6, l = tid & 63;
  const int fr = l & 15, fq = l >> 4;
  const int rt = w >> 1;     // row-tile (16 rows each)
  const int cs = w & 1;      // col-set
  f32x4 ai[3][4], ah[3][4];
#pragma unroll
  for (int g=0;g<3;g++)
#pragma unroll
    for (int q=0;q<4;q++){ ai[g][q] = (f32x4){0,0,0,0}; ah[g][q] = (f32x4){0,0,0,0}; }

#pragma unroll
  for (int kc=0;kc<4;kc++){
    short8 fa = *(const short8*)&Ahs[(rt*16 + fr)*136 + kc*32 + fq*8];
    short8 fx = *(const short8*)&Axs[(rt*16 + fr)*136 + kc*32 + fq*8];
#pragma unroll
    for (int g=0;g<3;g++)
#pragma unroll
      for (int q=0;q<4;q++){
        int ct = g*8 + cs*4 + q;
        size_t wo = (size_t)(ct*16 + fr)*HID + kc*32 + fq*8;
        short8 wi = *(const short8*)(Wi + wo);
        short8 wh = *(const short8*)(Wh + wo);
        ai[g][q] = __builtin_amdgcn_mfma_f32_16x16x32_bf16(fa, wi, ai[g][q], 0, 0, 0);
        ah[g][q] = __builtin_amdgcn_mfma_f32_16x16x32_bf16(fx, wh, ah[g][q], 0, 0, 0);
      }
  }

#pragma unroll
  for (int q=0;q<4;q++){
    int c0 = (cs*4 + q)*16 + fr;
    float bi_r = bih[c0], bi_z = bih[c0+128], bi_n = bih[c0+256];
    float bh_r = bhh[c0], bh_z = bhh[c0+128], bh_n = bhh[c0+256];
#pragma unroll
    for (int r4=0;r4<4;r4++){
      int row = bn + rt*16 + fq*4 + r4;
      if (row < rows){
        float rr = sigmf(ai[0][q][r4] + bi_r + ah[0][q][r4] + bh_r);
        float zz = sigmf(ai[1][q][r4] + bi_z + ah[1][q][r4] + bh_z);
        float nn = tanhf(ai[2][q][r4] + bi_n + rr*(ah[2][q][r4] + bh_n));
        float hv = Ax[(size_t)row*HID + c0];
        out[(size_t)row*HID + c0] = fmaxf((1.f - zz)*nn + zz*hv, 0.f);
      }
    }
  }
}

// ================= convert 8 GRU weight matrices fp32 -> bf16 ========================
__global__ void f2b8(const float* s0, const float* s1, const float* s2, const float* s3,
                     const float* s4, const float* s5, const float* s6, const float* s7,
                     unsigned short* __restrict__ dst)
{
  int i = (int)(blockIdx.x*256 + threadIdx.x);   // 0..49151
  int m = (int)blockIdx.y;
  const float* s;
  switch(m){
    case 0: s=s0; break; case 1: s=s1; break; case 2: s=s2; break; case 3: s=s3; break;
    case 4: s=s4; break; case 5: s=s5; break; case 6: s=s6; break; default: s=s7; break;
  }
  dst[(size_t)m*49152 + i] = bf16rne(s[i]);
}

// ================= rowdots ===========================================================
__global__ __launch_bounds__(256)
void rowdot(const float* __restrict__ A, const float* __restrict__ v,
            const float* __restrict__ bias, float* __restrict__ out, int rows)
{
  int wave = (int)((blockIdx.x * blockDim.x + threadIdx.x) >> 6);
  int lane = (int)(threadIdx.x & 63);
  if (wave >= rows) return;
  float2 a  = ((const float2*)(A + (size_t)wave*HID))[lane];
  float2 vv = ((const float2*)v)[lane];
  float s = a.x*vv.x + a.y*vv.y;
  for (int off=32; off; off>>=1) s += __shfl_down(s, off);
  if (lane==0) out[wave] = s + (bias ? bias[0] : 0.f);
}

__global__ __launch_bounds__(256)
void rowdot_b(const unsigned short* __restrict__ A, const float* __restrict__ v,
              float* __restrict__ out, int rows)
{
  int wave = (int)((blockIdx.x * blockDim.x + threadIdx.x) >> 6);
  int lane = (int)(threadIdx.x & 63);
  if (wave >= rows) return;
  unsigned aa = *(const unsigned*)(A + (size_t)wave*HID + lane*2);
  float2 vv = ((const float2*)v)[lane];
  float s = bf2f((unsigned short)(aa&0xffff))*vv.x + bf2f((unsigned short)(aa>>16))*vv.y;
  for (int off=32; off; off>>=1) s += __shfl_down(s, off);
  if (lane==0) out[wave] = s;
}

__global__ __launch_bounds__(256)
void rowdot2_b(const unsigned short* __restrict__ A, const float* __restrict__ v1,
               const float* __restrict__ v2, float* __restrict__ o1,
               float* __restrict__ o2, int rows)
{
  int wave = (int)((blockIdx.x * blockDim.x + threadIdx.x) >> 6);
  int lane = (int)(threadIdx.x & 63);
  if (wave >= rows) return;
  unsigned aa = *(const unsigned*)(A + (size_t)wave*HID + lane*2);
  float ax = bf2f((unsigned short)(aa&0xffff)), ay = bf2f((unsigned short)(aa>>16));
  float2 w1 = ((const float2*)v1)[lane];
  float2 w2 = ((const float2*)v2)[lane];
  float s1 = ax*w1.x + ay*w1.y;
  float s2 = ax*w2.x + ay*w2.y;
  for (int off=32; off; off>>=1){ s1 += __shfl_down(s1, off); s2 += __shfl_down(s2, off); }
  if (lane==0){ o1[wave]=s1; o2[wave]=s2; }
}

__global__ void colvec(const float* __restrict__ W, const float* __restrict__ v,
                       float* __restrict__ out)
{
  int k = (int)threadIdx.x;
  float s = 0.f;
  for (int j=0;j<HID;j++) s += W[j*HID+k]*v[j];
  out[k] = s;
}

// ================= CSR build =========================================================
__global__ void count_kernel(const int* __restrict__ idx, int* __restrict__ cnt, int n){
  int i = (int)(blockIdx.x*blockDim.x + threadIdx.x);
  if (i < n) atomicAdd(&cnt[idx[i]], 1);
}

__global__ __launch_bounds__(1024)
void scan_blocks(const int* __restrict__ cnt, int* __restrict__ off,
                 int* __restrict__ tot, int n)
{
  __shared__ int buf[1024];
  int i = (int)(blockIdx.x*1024 + threadIdx.x);
  int v = (i<n)? cnt[i] : 0;
  buf[threadIdx.x] = v;
  __syncthreads();
  for (int s=1;s<1024;s<<=1){
    int t = ((int)threadIdx.x >= s) ? buf[threadIdx.x - s] : 0;
    __syncthreads();
    buf[threadIdx.x] += t;
    __syncthreads();
  }
  if (i<n) off[i] = buf[threadIdx.x] - v;
  if (threadIdx.x==1023) tot[blockIdx.x] = buf[1023];
}

__global__ void scan_tot(int* __restrict__ tot, int* __restrict__ off_end, int nb){
  int lane = (int)threadIdx.x;
  int orig = (lane<nb)? tot[lane] : 0;
  int v = orig;
  for (int s=1;s<64;s<<=1){ int t = __shfl_up(v, s); if (lane>=s) v += t; }
  int total = __shfl(v, 63);
  if (lane<nb) tot[lane] = v - orig;
  if (lane==0) *off_end = total;
}

__global__ void scan_add(int* __restrict__ off, const int* __restrict__ tot, int n){
  int i = (int)(blockIdx.x*blockDim.x + threadIdx.x);
  if (i<n) off[i] += tot[i>>10];
}

__global__ void fill_kernel(const int* __restrict__ src, const int* __restrict__ dst,
                            const int* __restrict__ off, int* __restrict__ fill,
                            int* __restrict__ ssrc, int n){
  int e = (int)(blockIdx.x*blockDim.x + threadIdx.x);
  if (e < n){
    int d = dst[e];
    int p = off[d] + atomicAdd(&fill[d], 1);
    ssrc[p] = src[e];
  }
}

__global__ void graph_bounds(const int* __restrict__ batch, int* __restrict__ goff){
  int g = (int)(blockIdx.x*blockDim.x + threadIdx.x);
  if (g > NG) return;
  int lo=0, hi=NN;
  while (lo<hi){ int mid=(lo+hi)>>1; if (batch[mid] < g) lo=mid+1; else hi=mid; }
  goff[g] = lo;
}

// ================= pack Wg1[:, :128] and cg = rowsum(Wg1[:,128:153]) =================
__global__ void prep_gate(const float* __restrict__ Wg1, float* __restrict__ Wp,
                          float* __restrict__ cg){
  int j = (int)blockIdx.x;
  int t = (int)threadIdx.x;
  Wp[j*128 + t] = Wg1[j*153 + t];
  if (t == 0){
    float s = 0.f;
    for (int k=128;k<153;k++) s += Wg1[j*153+k];
    cg[j] = s;
  }
}

// ================= softmax aggregate over edges (LDS-staged, 2 edges/iter) ===========
__global__ __launch_bounds__(256)
void agg_edges(const int* __restrict__ off, const int* __restrict__ ssrc,
               const float* __restrict__ ls, const float* __restrict__ ld,
               const unsigned short* __restrict__ Mrows, const float* __restrict__ bias,
               float* __restrict__ out, int n)
{
  __shared__ float wbuf[4][64];
  __shared__ int   sbuf[4][64];
  const int ws = (int)(threadIdx.x >> 6);
  int node = (int)((blockIdx.x * blockDim.x + threadIdx.x) >> 6);
  int lane = (int)(threadIdx.x & 63);
  if (node >= n) return;
  int e0 = off[node], e1 = off[node+1];
  float ldv = ld[node];
  const int h = lane >> 5, cl = lane & 31;
  float denom = 0.f;
  float4 acc = make_float4(0.f,0.f,0.f,0.f);
  for (int j0=e0; j0<e1; j0+=64){
    int cnt = min(64, e1-j0);
    float wv = 0.f; int sc = 0;
    if (lane < cnt){
      sc = ssrc[j0+lane];
      wv = expf(leakyf(ls[sc]+ldv));
    }
    denom += wv;
    wbuf[ws][lane] = wv;
    sbuf[ws][lane] = sc;
#pragma unroll 4
    for (int k2=0;k2<cnt;k2+=2){
      float wk = wbuf[ws][k2+h];
      int  sck = sbuf[ws][k2+h];
      uint2 mm = *(const uint2*)(Mrows + (size_t)sck*HID + cl*4);
      acc.x += wk*bf2f((unsigned short)(mm.x&0xffff));
      acc.y += wk*bf2f((unsigned short)(mm.x>>16));
      acc.z += wk*bf2f((unsigned short)(mm.y&0xffff));
      acc.w += wk*bf2f((unsigned short)(mm.y>>16));
    }
  }
  acc.x += __shfl_xor(acc.x, 32); acc.y += __shfl_xor(acc.y, 32);
  acc.z += __shfl_xor(acc.z, 32); acc.w += __shfl_xor(acc.w, 32);
  for (int o=32;o;o>>=1) denom += __shfl_xor(denom, o);
  if (h==0){
    float inv = 1.f/(denom + 1e-16f);
    float4 b = *(const float4*)(bias + cl*4);
    float4 o;
    o.x = eluf(acc.x*inv + b.x); o.y = eluf(acc.y*inv + b.y);
    o.z = eluf(acc.z*inv + b.z); o.w = eluf(acc.w*inv + b.w);
    *(float4*)(out + (size_t)node*HID + cl*4) = o;
  }
}

// ================= readout kernels ===================================================
__global__ __launch_bounds__(256)
void graph_sum(const int* __restrict__ goff, const float* __restrict__ X,
               float* __restrict__ out)
{
  int g = (int)((blockIdx.x*blockDim.x + threadIdx.x) >> 6);
  int lane = (int)(threadIdx.x & 63);
  if (g >= NG) return;
  float2 acc = make_float2(0.f,0.f);
  for (int n=goff[g]; n<goff[g+1]; ++n){
    float2 v = ((const float2*)(X + (size_t)n*HID))[lane];
    acc.x += v.x; acc.y += v.y;
  }
  ((float2*)(out + (size_t)g*HID))[lane] = make_float2(fmaxf(acc.x,0.f), fmaxf(acc.y,0.f));
}

// fused: adst = dot(gout[g], vmd); then softmax aggregate over graph's node range
__global__ __launch_bounds__(256)
void graph_soft2(const int* __restrict__ goff, const float* __restrict__ asrc,
                 const float* __restrict__ gout, const float* __restrict__ vmd,
                 const unsigned short* __restrict__ Xt, const float* __restrict__ bias,
                 float* __restrict__ out)
{
  __shared__ float wbuf[4][64];
  const int ws = (int)(threadIdx.x >> 6);
  int g = (int)((blockIdx.x*blockDim.x + threadIdx.x) >> 6);
  int lane = (int)(threadIdx.x & 63);
  if (g >= NG) return;
  float2 ov = ((const float2*)(gout + (size_t)g*HID))[lane];
  float2 vv = ((const float2*)vmd)[lane];
  float ad = ov.x*vv.x + ov.y*vv.y;
  for (int o=32;o;o>>=1) ad += __shfl_xor(ad, o);
  int n0 = goff[g], n1 = goff[g+1];
  const int h = lane >> 5, cl = lane & 31;
  float denom = 0.f;
  float4 acc = make_float4(0.f,0.f,0.f,0.f);
  for (int j0=n0; j0<n1; j0+=64){
    int cnt = min(64, n1-j0);
    float wv = 0.f;
    if (lane < cnt) wv = expf(leakyf(asrc[j0+lane]+ad));
    denom += wv;
    wbuf[ws][lane] = wv;
#pragma unroll 4
    for (int k2=0;k2<cnt;k2+=2){
      float wk = wbuf[ws][k2+h];
      int rowi = min(j0 + k2 + h, n1 - 1);
      uint2 mm = *(const uint2*)(Xt + (size_t)rowi*HID + cl*4);
      acc.x += wk*bf2f((unsigned short)(mm.x&0xffff));
      acc.y += wk*bf2f((unsigned short)(mm.x>>16));
      acc.z += wk*bf2f((unsigned short)(mm.y&0xffff));
      acc.w += wk*bf2f((unsigned short)(mm.y>>16));
    }
  }
  acc.x += __shfl_xor(acc.x, 32); acc.y += __shfl_xor(acc.y, 32);
  acc.z += __shfl_xor(acc.z, 32); acc.w += __shfl_xor(acc.w, 32);
  for (int o=32;o;o>>=1) denom += __shfl_xor(denom, o);
  if (h==0){
    float inv = 1.f/(denom + 1e-16f);
    float4 b = *(const float4*)(bias + cl*4);
    float4 o;
    o.x = eluf(acc.x*inv + b.x); o.y = eluf(acc.y*inv + b.y);
    o.z = eluf(acc.z*inv + b.z); o.w = eluf(acc.w*inv + b.w);
    *(float4*)(out + (size_t)g*HID + cl*4) = o;
  }
}

// =====================================================================================
extern "C" void kernel_launch(void* const* d_in, const int* in_sizes, int n_in,
                              void* d_out, int out_size, void* d_ws, size_t ws_size,
                              hipStream_t stream)
{
  const float* x_in  = (const float*)d_in[0];
  const int*   ei    = (const int*)d_in[1];
  const int*   batch = (const int*)d_in[2];
  const float* W1    = (const float*)d_in[3];
  const float* b1    = (const float*)d_in[4];
  const float* Wg1   = (const float*)d_in[5];
  const float* att_l = (const float*)d_in[6];
  const float* att_r = (const float*)d_in[7];
  const float* Wg2   = (const float*)d_in[8];
  const float* bg    = (const float*)d_in[9];
  const float* Wih0  = (const float*)d_in[10];
  const float* Whh0  = (const float*)d_in[11];
  const float* bih0  = (const float*)d_in[12];
  const float* bhh0  = (const float*)d_in[13];
  const float* Wa    = (const float*)d_in[14];
  const float* att_src_a = (const float*)d_in[15];
  const float* att_dst_a = (const float*)d_in[16];
  const float* ba    = (const float*)d_in[17];
  const float* Wih_a = (const float*)d_in[18];
  const float* Whh_a = (const float*)d_in[19];
  const float* bih_a = (const float*)d_in[20];
  const float* bhh_a = (const float*)d_in[21];
  const float* Wm    = (const float*)d_in[22];
  const float* att_src_m = (const float*)d_in[23];
  const float* att_dst_m = (const float*)d_in[24];
  const float* bm    = (const float*)d_in[25];
  const float* Wih_m = (const float*)d_in[26];
  const float* Whh_m = (const float*)d_in[27];
  const float* bih_m = (const float*)d_in[28];
  const float* bhh_m = (const float*)d_in[29];
  const float* W2    = (const float*)d_in[30];
  const float* b2    = (const float*)d_in[31];
  (void)in_sizes; (void)n_in; (void)out_size; (void)ws_size;

  char* wsb = (char*)d_ws;
  size_t off = 0;
  auto alloc = [&](size_t bytes)->void* {
    void* p = wsb + off;
    off += (bytes + 255) & ~(size_t)255;
    return p;
  };
  float* f_x   = (float*)alloc((size_t)NN*HID*4);
  float* f_h   = (float*)alloc((size_t)NN*HID*4);
  unsigned short* f_t = (unsigned short*)alloc((size_t)NN*HID*2);
  float* f_s1  = (float*)alloc((size_t)NN*4);
  float* f_s2  = (float*)alloc((size_t)NN*4);
  float* g_out = (float*)alloc((size_t)NG*HID*4);
  float* g_h   = (float*)alloc((size_t)NG*HID*4);
  float* w_g1p = (float*)alloc((size_t)HID*HID*4);
  float* w_cg  = (float*)alloc((size_t)HID*4);
  float* w_vmd = (float*)alloc((size_t)HID*4);
  unsigned short* w_b = (unsigned short*)alloc((size_t)8*49152*2); // 8 GRU weight mats bf16
  int* i_cnt   = (int*)alloc((size_t)NN*4);
  int* i_off   = (int*)alloc((size_t)(NN+1)*4);
  int* i_fill  = (int*)alloc((size_t)NN*4);
  int* i_src   = (int*)alloc((size_t)NE*4);
  int* i_tot   = (int*)alloc((size_t)64*4);
  int* i_goff  = (int*)alloc((size_t)(NG+1)*4);

  const int* e_src = ei;
  const int* e_dst = ei + NE;

  hipMemsetAsync(i_cnt, 0, (size_t)NN*4, stream);
  hipMemsetAsync(i_fill, 0, (size_t)NN*4, stream);

  const int NB = (NN + 1023)/1024;
  count_kernel<<<(NE+255)/256,256,0,stream>>>(e_dst, i_cnt, NE);
  scan_blocks<<<NB,1024,0,stream>>>(i_cnt, i_off, i_tot, NN);
  scan_tot<<<1,64,0,stream>>>(i_tot, i_off+NN, NB);
  scan_add<<<(NN+255)/256,256,0,stream>>>(i_off, i_tot, NN);
  fill_kernel<<<(NE+255)/256,256,0,stream>>>(e_src, e_dst, i_off, i_fill, i_src, NE);
  graph_bounds<<<(NG+1+255)/256,256,0,stream>>>(batch, i_goff);
  prep_gate<<<128,128,0,stream>>>(Wg1, w_g1p, w_cg);
  colvec<<<1,128,0,stream>>>(Wm, att_dst_m, w_vmd);
  f2b8<<<dim3(192,8),256,0,stream>>>(Wih0, Whh0, Wih_a, Whh_a,
                                     Wih_a + (size_t)384*HID, Whh_a + (size_t)384*HID,
                                     Wih_m, Whh_m, w_b);
  unsigned short* b_wih0  = w_b + 0*49152;
  unsigned short* b_whh0  = w_b + 1*49152;
  unsigned short* b_wiha0 = w_b + 2*49152;
  unsigned short* b_whha0 = w_b + 3*49152;
  unsigned short* b_wiha1 = w_b + 4*49152;
  unsigned short* b_whha1 = w_b + 5*49152;
  unsigned short* b_wihm  = w_b + 6*49152;
  unsigned short* b_whhm  = w_b + 7*49152;

  const int GB = (NN+63)/64;                 // gemm64 row blocks
  const int FB = (NN+31)/32;                 // fused_gru row blocks
  const int wavegrid_n = (NN*64+255)/256;
  const int wavegrid_g = (NG*64)/256;

  // x = leaky(x @ W1.T + b1)
  gemm64<64><<<GB,256,0,stream>>>(x_in, W1, b1, f_x, nullptr, NN, 1);

  // ---- GATEConv ----
  gemm64<128><<<GB,256,0,stream>>>(f_x, w_g1p, w_cg, nullptr, f_t, NN, 1);   // xe bf16
  rowdot_b<<<wavegrid_n,256,0,stream>>>(f_t, att_l, f_s1, NN);
  rowdot  <<<wavegrid_n,256,0,stream>>>(f_x, att_r, nullptr, f_s2, NN);
  gemm64<128><<<GB,256,0,stream>>>(f_x, Wg2, nullptr, nullptr, f_t, NN, 0);  // xg2 bf16
  agg_edges<<<(NN+3)/4,256,0,stream>>>(i_off, i_src, f_s1, f_s2, f_t, bg, f_h, NN);
  fused_gru<<<FB,256,0,stream>>>(f_h, f_x, b_wih0, b_whh0, bih0, bhh0, f_x, NN);

  // ---- 2x GATConv + GRU ----
  for (int l=0;l<2;l++){
    gemm64<128><<<GB,256,0,stream>>>(f_x, Wa + (size_t)l*HID*HID, nullptr, nullptr, f_t, NN, 0);
    rowdot2_b<<<wavegrid_n,256,0,stream>>>(f_t, att_src_a + l*HID, att_dst_a + l*HID, f_s1, f_s2, NN);
    agg_edges<<<(NN+3)/4,256,0,stream>>>(i_off, i_src, f_s1, f_s2, f_t, ba + l*HID, f_h, NN);
    fused_gru<<<FB,256,0,stream>>>(f_h, f_x,
                                   l ? b_wiha1 : b_wiha0, l ? b_whha1 : b_whha0,
                                   bih_a + l*384, bhh_a + l*384, f_x, NN);
  }

  // ---- attentive readout ----
  graph_sum<<<wavegrid_g,256,0,stream>>>(i_goff, f_x, g_out);
  gemm64<128><<<GB,256,0,stream>>>(f_x, Wm, nullptr, nullptr, f_t, NN, 0);   // xt bf16
  rowdot_b<<<wavegrid_n,256,0,stream>>>(f_t, att_src_m, f_s1, NN);
  for (int t=0;t<3;t++){
    graph_soft2<<<wavegrid_g,256,0,stream>>>(i_goff, f_s1, g_out, w_vmd, f_t, bm, g_h);
    fused_gru<<<(NG+31)/32,256,0,stream>>>(g_h, g_out, b_wihm, b_whhm, bih_m, bhh_m, g_out, NG);
  }

  rowdot<<<wavegrid_g,256,0,stream>>>(g_out, W2, b2, (float*)d_out, NG);
}

// Round 5
// 662.960 us; speedup vs baseline: 2.7012x; 1.3399x over previous
//
#include <hip/hip_runtime.h>
#include <math.h>

#define NN 50000
#define NE 800000
#define NG 1024
#define HID 128

typedef __attribute__((ext_vector_type(8))) short short8;
typedef __attribute__((ext_vector_type(4))) unsigned short ushort4v;
typedef __attribute__((ext_vector_type(4))) float f32x4;

__device__ __forceinline__ float leakyf(float v){ return v >= 0.f ? v : 0.01f*v; }
__device__ __forceinline__ float sigmf(float v){ return 1.f/(1.f+expf(-v)); }
__device__ __forceinline__ float eluf(float v){ return v > 0.f ? v : expm1f(v); }
__device__ __forceinline__ unsigned short bf16rne(float f){
  union { float f; unsigned u; } v; v.f = f;
  return (unsigned short)((v.u + 0x7FFFu + ((v.u >> 16) & 1u)) >> 16);
}
__device__ __forceinline__ float bf2f(unsigned short h){
  union { unsigned u; float f; } v; v.u = ((unsigned)h) << 16; return v.f;
}
__device__ __forceinline__ short8 cvt8(const float* a){
  short8 r;
#pragma unroll
  for (int j=0;j<8;j++) r[j] = (short)bf16rne(a[j]);
  return r;
}

// ======== pack weights fp32 row-major -> bf16 MFMA B-fragment order ==================
// frag layout: dst[doff + (t*64 + lane)*8 + j] = W[ct*16 + (lane&15)][kc*32 + (lane>>4)*8 + j]
// where t = ct*(K/32) + kc. Wave load of one (ct,kc) tile = contiguous 1 KB.
__global__ __launch_bounds__(256)
void pack_all(const float* W1, const float* Wg1, const float* Wg2, const float* Wa,
              const float* Wm, const float* Wih0, const float* Whh0,
              const float* Wih_a, const float* Whh_a, const float* Wih_m,
              const float* Whh_m, unsigned short* __restrict__ dst)
{
  int m = (int)blockIdx.y;
  int t = (int)blockIdx.x*4 + ((int)threadIdx.x>>6);
  int l = (int)threadIdx.x & 63;
  const float* src; int stride=128, M=128, K=128; size_t doff;
  switch(m){
    case 0:  src=W1;    stride=64;  K=64;  doff=0;      break;
    case 1:  src=Wg1;   stride=153;        doff=8192;   break;
    case 2:  src=Wg2;                      doff=24576;  break;
    case 3:  src=Wa;                       doff=40960;  break;
    case 4:  src=Wa+16384;                 doff=57344;  break;
    case 5:  src=Wm;                       doff=73728;  break;
    case 6:  src=Wih0;  M=384;             doff=90112;  break;
    case 7:  src=Whh0;  M=384;             doff=139264; break;
    case 8:  src=Wih_a; M=384;             doff=188416; break;
    case 9:  src=Whh_a; M=384;             doff=237568; break;
    case 10: src=Wih_a+49152; M=384;       doff=286720; break;
    case 11: src=Whh_a+49152; M=384;       doff=335872; break;
    case 12: src=Wih_m; M=384;             doff=385024; break;
    default: src=Whh_m; M=384;             doff=434176; break;
  }
  int tk = K/32;
  if (t >= (M/16)*tk) return;
  int ct = t / tk, kc = t % tk;
  int row = ct*16 + (l&15);
  int col = kc*32 + ((l>>4)<<3);
  unsigned short o[8];
#pragma unroll
  for (int j=0;j<8;j++) o[j] = bf16rne(src[(size_t)row*stride + col + j]);
  ushort4v* d = (ushort4v*)(dst + doff + (((size_t)t*64 + l)<<3));
  ushort4v d0; d0.x=o[0]; d0.y=o[1]; d0.z=o[2]; d0.w=o[3];
  ushort4v d1; d1.x=o[4]; d1.y=o[5]; d1.z=o[6]; d1.w=o[7];
  d[0]=d0; d[1]=d1;
}

// ================= gemm_direct: 32 rows x 128 cols per block, packed bf16 W ==========
// C[r,m] = act(sum_k A[r,k]*W[m,k] + bias[m]). A: rows x K fp32. Wp: packed bf16.
// Optional fused dots: s1[r]=C.v1, s2[r]=C.v2 (post-act), or s2[r]=A.va (GATEConv er).
template<int K>
__global__ __launch_bounds__(256)
void gemm_direct(const float* __restrict__ A, const unsigned short* __restrict__ Wp,
                 const float* __restrict__ bias, float* __restrict__ Cf,
                 unsigned short* __restrict__ Cb,
                 const float* __restrict__ v1, const float* __restrict__ v2,
                 const float* __restrict__ va,
                 float* __restrict__ s1, float* __restrict__ s2, int rows, int act)
{
  __shared__ float sd1[2][32];
  __shared__ float sd2[2][32];
  constexpr int KC = K/32;
  const int tid=(int)threadIdx.x, w=tid>>6, l=tid&63;
  const int fr=l&15, fq=l>>4;
  const int rt=w>>1, ch=w&1;
  const int bn = (int)blockIdx.x*32;
  const int ar = bn + rt*16 + fr;
  f32x4 acc[4];
#pragma unroll
  for (int j=0;j<4;j++) acc[j] = (f32x4){0.f,0.f,0.f,0.f};
  float pa = 0.f;
#pragma unroll
  for (int kc=0;kc<KC;kc++){
    float a8[8];
    if (ar < rows){
      *(float4*)&a8[0] = *(const float4*)(A + (size_t)ar*K + kc*32 + fq*8);
      *(float4*)&a8[4] = *(const float4*)(A + (size_t)ar*K + kc*32 + fq*8 + 4);
    } else {
#pragma unroll
      for (int j=0;j<8;j++) a8[j]=0.f;
    }
    short8 fa = cvt8(a8);
    if (va && ch==0){
      float4 t0 = *(const float4*)(va + kc*32 + fq*8);
      float4 t1 = *(const float4*)(va + kc*32 + fq*8 + 4);
      pa += a8[0]*t0.x + a8[1]*t0.y + a8[2]*t0.z + a8[3]*t0.w
          + a8[4]*t1.x + a8[5]*t1.y + a8[6]*t1.z + a8[7]*t1.w;
    }
#pragma unroll
    for (int j=0;j<4;j++){
      const short8 bfr = *(const short8*)(Wp + ((((size_t)(ch*4+j)*KC + kc)*64 + l)<<3));
      acc[j] = __builtin_amdgcn_mfma_f32_16x16x32_bf16(fa, bfr, acc[j], 0, 0, 0);
    }
  }
  // epilogue: C/D layout col=lane&15, row=(lane>>4)*4+reg
  float dp1[4]={0.f,0.f,0.f,0.f}, dp2[4]={0.f,0.f,0.f,0.f};
#pragma unroll
  for (int j=0;j<4;j++){
    int c = ch*64 + j*16 + fr;
    float bv = bias ? bias[c] : 0.f;
    float w1 = v1 ? v1[c] : 0.f;
    float w2 = v2 ? v2[c] : 0.f;
#pragma unroll
    for (int r4=0;r4<4;r4++){
      float o = acc[j][r4] + bv;
      if (act) o = leakyf(o);
      dp1[r4] += o*w1; dp2[r4] += o*w2;
      int r = bn + rt*16 + fq*4 + r4;
      if (r < rows){
        if (Cf) Cf[(size_t)r*HID + c] = o;
        if (Cb) Cb[(size_t)r*HID + c] = bf16rne(o);
      }
    }
  }
  if (v1){
#pragma unroll
    for (int r4=0;r4<4;r4++){
#pragma unroll
      for (int m=1;m<16;m<<=1){ dp1[r4] += __shfl_xor(dp1[r4], m); dp2[r4] += __shfl_xor(dp2[r4], m); }
    }
    if (fr==0){
#pragma unroll
      for (int r4=0;r4<4;r4++){
        sd1[ch][rt*16 + fq*4 + r4] = dp1[r4];
        sd2[ch][rt*16 + fq*4 + r4] = dp2[r4];
      }
    }
    __syncthreads();
    if (tid < 32){
      int r = bn + tid;
      if (r < rows) s1[r] = sd1[0][tid] + sd1[1][tid];
    } else if (v2 && tid < 64){
      int r = bn + tid - 32;
      if (r < rows) s2[r] = sd2[0][tid-32] + sd2[1][tid-32];
    }
  }
  if (va && ch==0){
    pa += __shfl_xor(pa, 16); pa += __shfl_xor(pa, 32);
    if (fq==0){
      int r = bn + rt*16 + fr;
      if (r < rows) s2[r] = pa;
    }
  }
}

// ================= fused GRU v2: direct frags, packed weights, no LDS ================
// out = relu(gru(gi = Ah@Wi^T+bih, gh = Ax@Whh^T+bhh, h=Ax)). out MUST NOT alias Ax.
// block = 256 thr, 16 rows; wave cq owns cols [cq*32, cq*32+32) x 3 gates x 2 mats.
__global__ __launch_bounds__(256)
void fused_gru(const float* __restrict__ Ah, const float* __restrict__ Ax,
               const unsigned short* __restrict__ Wi, const unsigned short* __restrict__ Wh,
               const float* __restrict__ bih, const float* __restrict__ bhh,
               float* __restrict__ out, int rows)
{
  const int tid=(int)threadIdx.x, cq=tid>>6, l=tid&63;
  const int fr=l&15, fq=l>>4;
  const int bn = (int)blockIdx.x*16;
  const int ar = bn + fr;
  f32x4 ai[3][2], ah[3][2];
#pragma unroll
  for (int g=0;g<3;g++)
#pragma unroll
    for (int t=0;t<2;t++){ ai[g][t] = (f32x4){0,0,0,0}; ah[g][t] = (f32x4){0,0,0,0}; }
#pragma unroll
  for (int kc=0;kc<4;kc++){
    float a8[8], x8[8];
    if (ar < rows){
      *(float4*)&a8[0] = *(const float4*)(Ah + (size_t)ar*HID + kc*32 + fq*8);
      *(float4*)&a8[4] = *(const float4*)(Ah + (size_t)ar*HID + kc*32 + fq*8 + 4);
      *(float4*)&x8[0] = *(const float4*)(Ax + (size_t)ar*HID + kc*32 + fq*8);
      *(float4*)&x8[4] = *(const float4*)(Ax + (size_t)ar*HID + kc*32 + fq*8 + 4);
    } else {
#pragma unroll
      for (int j=0;j<8;j++){ a8[j]=0.f; x8[j]=0.f; }
    }
    short8 fa = cvt8(a8), fx = cvt8(x8);
#pragma unroll
    for (int g=0;g<3;g++)
#pragma unroll
      for (int t=0;t<2;t++){
        size_t woff = ((((size_t)(g*8 + cq*2 + t)*4 + kc)*64 + l)<<3);
        short8 wi = *(const short8*)(Wi + woff);
        short8 wh = *(const short8*)(Wh + woff);
        ai[g][t] = __builtin_amdgcn_mfma_f32_16x16x32_bf16(fa, wi, ai[g][t], 0, 0, 0);
        ah[g][t] = __builtin_amdgcn_mfma_f32_16x16x32_bf16(fx, wh, ah[g][t], 0, 0, 0);
      }
  }
#pragma unroll
  for (int t=0;t<2;t++){
    int c0 = (cq*2+t)*16 + fr;
    float bi_r=bih[c0], bi_z=bih[c0+128], bi_n=bih[c0+256];
    float bh_r=bhh[c0], bh_z=bhh[c0+128], bh_n=bhh[c0+256];
#pragma unroll
    for (int r4=0;r4<4;r4++){
      int row = bn + fq*4 + r4;
      if (row < rows){
        float rr = sigmf(ai[0][t][r4]+bi_r+ah[0][t][r4]+bh_r);
        float zz = sigmf(ai[1][t][r4]+bi_z+ah[1][t][r4]+bh_z);
        float nn = tanhf(ai[2][t][r4]+bi_n + rr*(ah[2][t][r4]+bh_n));
        float hv = Ax[(size_t)row*HID + c0];
        out[(size_t)row*HID + c0] = fmaxf((1.f-zz)*nn + zz*hv, 0.f);
      }
    }
  }
}

// ================= rowdot (final output) =============================================
__global__ __launch_bounds__(256)
void rowdot(const float* __restrict__ A, const float* __restrict__ v,
            const float* __restrict__ bias, float* __restrict__ out, int rows)
{
  int wave = (int)((blockIdx.x * blockDim.x + threadIdx.x) >> 6);
  int lane = (int)(threadIdx.x & 63);
  if (wave >= rows) return;
  float2 a  = ((const float2*)(A + (size_t)wave*HID))[lane];
  float2 vv = ((const float2*)v)[lane];
  float s = a.x*vv.x + a.y*vv.y;
  for (int off=32; off; off>>=1) s += __shfl_down(s, off);
  if (lane==0) out[wave] = s + (bias ? bias[0] : 0.f);
}

__global__ void colvec(const float* __restrict__ W, const float* __restrict__ v,
                       float* __restrict__ out)
{
  int k = (int)threadIdx.x;
  float s = 0.f;
  for (int j=0;j<HID;j++) s += W[j*HID+k]*v[j];
  out[k] = s;
}

__global__ void prep_cg(const float* __restrict__ Wg1, float* __restrict__ cg){
  int j = (int)threadIdx.x;
  float s = 0.f;
  for (int k=128;k<153;k++) s += Wg1[j*153+k];
  cg[j] = s;
}

// ================= CSR build =========================================================
__global__ void count_kernel(const int* __restrict__ idx, int* __restrict__ cnt, int n){
  int i = (int)(blockIdx.x*blockDim.x + threadIdx.x);
  if (i < n) atomicAdd(&cnt[idx[i]], 1);
}

__global__ __launch_bounds__(1024)
void scan_blocks(const int* __restrict__ cnt, int* __restrict__ off,
                 int* __restrict__ tot, int n)
{
  __shared__ int buf[1024];
  int i = (int)(blockIdx.x*1024 + threadIdx.x);
  int v = (i<n)? cnt[i] : 0;
  buf[threadIdx.x] = v;
  __syncthreads();
  for (int s=1;s<1024;s<<=1){
    int t = ((int)threadIdx.x >= s) ? buf[threadIdx.x - s] : 0;
    __syncthreads();
    buf[threadIdx.x] += t;
    __syncthreads();
  }
  if (i<n) off[i] = buf[threadIdx.x] - v;
  if (threadIdx.x==1023) tot[blockIdx.x] = buf[1023];
}

__global__ void scan_tot(int* __restrict__ tot, int* __restrict__ off_end, int nb){
  int lane = (int)threadIdx.x;
  int orig = (lane<nb)? tot[lane] : 0;
  int v = orig;
  for (int s=1;s<64;s<<=1){ int t = __shfl_up(v, s); if (lane>=s) v += t; }
  int total = __shfl(v, 63);
  if (lane<nb) tot[lane] = v - orig;
  if (lane==0) *off_end = total;
}

__global__ void scan_add(int* __restrict__ off, const int* __restrict__ tot, int n){
  int i = (int)(blockIdx.x*blockDim.x + threadIdx.x);
  if (i<n) off[i] += tot[i>>10];
}

__global__ void fill_kernel(const int* __restrict__ src, const int* __restrict__ dst,
                            const int* __restrict__ off, int* __restrict__ fill,
                            int* __restrict__ ssrc, int n){
  int e = (int)(blockIdx.x*blockDim.x + threadIdx.x);
  if (e < n){
    int d = dst[e];
    int p = off[d] + atomicAdd(&fill[d], 1);
    ssrc[p] = src[e];
  }
}

__global__ void graph_bounds(const int* __restrict__ batch, int* __restrict__ goff){
  int g = (int)(blockIdx.x*blockDim.x + threadIdx.x);
  if (g > NG) return;
  int lo=0, hi=NN;
  while (lo<hi){ int mid=(lo+hi)>>1; if (batch[mid] < g) lo=mid+1; else hi=mid; }
  goff[g] = lo;
}

// ================= softmax aggregate over edges ======================================
__global__ __launch_bounds__(256)
void agg_edges(const int* __restrict__ off, const int* __restrict__ ssrc,
               const float* __restrict__ ls, const float* __restrict__ ld,
               const unsigned short* __restrict__ Mrows, const float* __restrict__ bias,
               float* __restrict__ out, int n)
{
  __shared__ float wbuf[4][64];
  __shared__ int   sbuf[4][64];
  const int ws = (int)(threadIdx.x >> 6);
  int node = (int)((blockIdx.x * blockDim.x + threadIdx.x) >> 6);
  int lane = (int)(threadIdx.x & 63);
  if (node >= n) return;
  int e0 = off[node], e1 = off[node+1];
  float ldv = ld[node];
  const int h = lane >> 5, cl = lane & 31;
  float denom = 0.f;
  float4 acc = make_float4(0.f,0.f,0.f,0.f);
  for (int j0=e0; j0<e1; j0+=64){
    int cnt = min(64, e1-j0);
    float wv = 0.f; int sc = 0;
    if (lane < cnt){
      sc = ssrc[j0+lane];
      wv = expf(leakyf(ls[sc]+ldv));
    }
    denom += wv;
    wbuf[ws][lane] = wv;
    sbuf[ws][lane] = sc;
#pragma unroll 4
    for (int k2=0;k2<cnt;k2+=2){
      float wk = wbuf[ws][k2+h];
      int  sck = sbuf[ws][k2+h];
      uint2 mm = *(const uint2*)(Mrows + (size_t)sck*HID + cl*4);
      acc.x += wk*bf2f((unsigned short)(mm.x&0xffff));
      acc.y += wk*bf2f((unsigned short)(mm.x>>16));
      acc.z += wk*bf2f((unsigned short)(mm.y&0xffff));
      acc.w += wk*bf2f((unsigned short)(mm.y>>16));
    }
  }
  acc.x += __shfl_xor(acc.x, 32); acc.y += __shfl_xor(acc.y, 32);
  acc.z += __shfl_xor(acc.z, 32); acc.w += __shfl_xor(acc.w, 32);
  for (int o=32;o;o>>=1) denom += __shfl_xor(denom, o);
  if (h==0){
    float inv = 1.f/(denom + 1e-16f);
    float4 b = *(const float4*)(bias + cl*4);
    float4 o;
    o.x = eluf(acc.x*inv + b.x); o.y = eluf(acc.y*inv + b.y);
    o.z = eluf(acc.z*inv + b.z); o.w = eluf(acc.w*inv + b.w);
    *(float4*)(out + (size_t)node*HID + cl*4) = o;
  }
}

// ================= readout kernels ===================================================
__global__ __launch_bounds__(256)
void graph_sum(const int* __restrict__ goff, const float* __restrict__ X,
               float* __restrict__ out)
{
  int g = (int)((blockIdx.x*blockDim.x + threadIdx.x) >> 6);
  int lane = (int)(threadIdx.x & 63);
  if (g >= NG) return;
  float2 acc = make_float2(0.f,0.f);
  for (int n=goff[g]; n<goff[g+1]; ++n){
    float2 v = ((const float2*)(X + (size_t)n*HID))[lane];
    acc.x += v.x; acc.y += v.y;
  }
  ((float2*)(out + (size_t)g*HID))[lane] = make_float2(fmaxf(acc.x,0.f), fmaxf(acc.y,0.f));
}

__global__ __launch_bounds__(256)
void graph_soft2(const int* __restrict__ goff, const float* __restrict__ asrc,
                 const float* __restrict__ gout, const float* __restrict__ vmd,
                 const unsigned short* __restrict__ Xt, const float* __restrict__ bias,
                 float* __restrict__ out)
{
  __shared__ float wbuf[4][64];
  const int ws = (int)(threadIdx.x >> 6);
  int g = (int)((blockIdx.x*blockDim.x + threadIdx.x) >> 6);
  int lane = (int)(threadIdx.x & 63);
  if (g >= NG) return;
  float2 ov = ((const float2*)(gout + (size_t)g*HID))[lane];
  float2 vv = ((const float2*)vmd)[lane];
  float ad = ov.x*vv.x + ov.y*vv.y;
  for (int o=32;o;o>>=1) ad += __shfl_xor(ad, o);
  int n0 = goff[g], n1 = goff[g+1];
  const int h = lane >> 5, cl = lane & 31;
  float denom = 0.f;
  float4 acc = make_float4(0.f,0.f,0.f,0.f);
  for (int j0=n0; j0<n1; j0+=64){
    int cnt = min(64, n1-j0);
    float wv = 0.f;
    if (lane < cnt) wv = expf(leakyf(asrc[j0+lane]+ad));
    denom += wv;
    wbuf[ws][lane] = wv;
#pragma unroll 4
    for (int k2=0;k2<cnt;k2+=2){
      float wk = wbuf[ws][k2+h];
      int rowi = min(j0 + k2 + h, n1 - 1);
      uint2 mm = *(const uint2*)(Xt + (size_t)rowi*HID + cl*4);
      acc.x += wk*bf2f((unsigned short)(mm.x&0xffff));
      acc.y += wk*bf2f((unsigned short)(mm.x>>16));
      acc.z += wk*bf2f((unsigned short)(mm.y&0xffff));
      acc.w += wk*bf2f((unsigned short)(mm.y>>16));
    }
  }
  acc.x += __shfl_xor(acc.x, 32); acc.y += __shfl_xor(acc.y, 32);
  acc.z += __shfl_xor(acc.z, 32); acc.w += __shfl_xor(acc.w, 32);
  for (int o=32;o;o>>=1) denom += __shfl_xor(denom, o);
  if (h==0){
    float inv = 1.f/(denom + 1e-16f);
    float4 b = *(const float4*)(bias + cl*4);
    float4 o;
    o.x = eluf(acc.x*inv + b.x); o.y = eluf(acc.y*inv + b.y);
    o.z = eluf(acc.z*inv + b.z); o.w = eluf(acc.w*inv + b.w);
    *(float4*)(out + (size_t)g*HID + cl*4) = o;
  }
}

// =====================================================================================
extern "C" void kernel_launch(void* const* d_in, const int* in_sizes, int n_in,
                              void* d_out, int out_size, void* d_ws, size_t ws_size,
                              hipStream_t stream)
{
  const float* x_in  = (const float*)d_in[0];
  const int*   ei    = (const int*)d_in[1];
  const int*   batch = (const int*)d_in[2];
  const float* W1    = (const float*)d_in[3];
  const float* b1    = (const float*)d_in[4];
  const float* Wg1   = (const float*)d_in[5];
  const float* att_l = (const float*)d_in[6];
  const float* att_r = (const float*)d_in[7];
  const float* Wg2   = (const float*)d_in[8];
  const float* bg    = (const float*)d_in[9];
  const float* Wih0  = (const float*)d_in[10];
  const float* Whh0  = (const float*)d_in[11];
  const float* bih0  = (const float*)d_in[12];
  const float* bhh0  = (const float*)d_in[13];
  const float* Wa    = (const float*)d_in[14];
  const float* att_src_a = (const float*)d_in[15];
  const float* att_dst_a = (const float*)d_in[16];
  const float* ba    = (const float*)d_in[17];
  const float* Wih_a = (const float*)d_in[18];
  const float* Whh_a = (const float*)d_in[19];
  const float* bih_a = (const float*)d_in[20];
  const float* bhh_a = (const float*)d_in[21];
  const float* Wm    = (const float*)d_in[22];
  const float* att_src_m = (const float*)d_in[23];
  const float* att_dst_m = (const float*)d_in[24];
  const float* bm    = (const float*)d_in[25];
  const float* Wih_m = (const float*)d_in[26];
  const float* Whh_m = (const float*)d_in[27];
  const float* bih_m = (const float*)d_in[28];
  const float* bhh_m = (const float*)d_in[29];
  const float* W2    = (const float*)d_in[30];
  const float* b2    = (const float*)d_in[31];
  (void)in_sizes; (void)n_in; (void)out_size; (void)ws_size;

  char* wsb = (char*)d_ws;
  size_t off = 0;
  auto alloc = [&](size_t bytes)->void* {
    void* p = wsb + off;
    off += (bytes + 255) & ~(size_t)255;
    return p;
  };
  float* f_x   = (float*)alloc((size_t)NN*HID*4);
  float* f_xb  = (float*)alloc((size_t)NN*HID*4);
  float* f_h   = (float*)alloc((size_t)NN*HID*4);
  unsigned short* f_t = (unsigned short*)alloc((size_t)NN*HID*2);
  float* f_s1  = (float*)alloc((size_t)NN*4);
  float* f_s2  = (float*)alloc((size_t)NN*4);
  float* g_o0  = (float*)alloc((size_t)NG*HID*4);
  float* g_o1  = (float*)alloc((size_t)NG*HID*4);
  float* g_h   = (float*)alloc((size_t)NG*HID*4);
  float* w_cg  = (float*)alloc((size_t)HID*4);
  float* w_vmd = (float*)alloc((size_t)HID*4);
  unsigned short* w_pack = (unsigned short*)alloc((size_t)483328*2);
  int* i_cnt   = (int*)alloc((size_t)NN*4);
  int* i_off   = (int*)alloc((size_t)(NN+1)*4);
  int* i_fill  = (int*)alloc((size_t)NN*4);
  int* i_src   = (int*)alloc((size_t)NE*4);
  int* i_tot   = (int*)alloc((size_t)64*4);
  int* i_goff  = (int*)alloc((size_t)(NG+1)*4);

  const unsigned short* pk_W1   = w_pack + 0;
  const unsigned short* pk_g1   = w_pack + 8192;
  const unsigned short* pk_g2   = w_pack + 24576;
  const unsigned short* pk_wa0  = w_pack + 40960;
  const unsigned short* pk_wa1  = w_pack + 57344;
  const unsigned short* pk_wm   = w_pack + 73728;
  const unsigned short* pk_wih0 = w_pack + 90112;
  const unsigned short* pk_whh0 = w_pack + 139264;
  const unsigned short* pk_wiha0= w_pack + 188416;
  const unsigned short* pk_whha0= w_pack + 237568;
  const unsigned short* pk_wiha1= w_pack + 286720;
  const unsigned short* pk_whha1= w_pack + 335872;
  const unsigned short* pk_wihm = w_pack + 385024;
  const unsigned short* pk_whhm = w_pack + 434176;

  const int* e_src = ei;
  const int* e_dst = ei + NE;

  hipMemsetAsync(i_cnt, 0, (size_t)NN*4, stream);
  hipMemsetAsync(i_fill, 0, (size_t)NN*4, stream);

  const int NB = (NN + 1023)/1024;
  count_kernel<<<(NE+255)/256,256,0,stream>>>(e_dst, i_cnt, NE);
  scan_blocks<<<NB,1024,0,stream>>>(i_cnt, i_off, i_tot, NN);
  scan_tot<<<1,64,0,stream>>>(i_tot, i_off+NN, NB);
  scan_add<<<(NN+255)/256,256,0,stream>>>(i_off, i_tot, NN);
  fill_kernel<<<(NE+255)/256,256,0,stream>>>(e_src, e_dst, i_off, i_fill, i_src, NE);
  graph_bounds<<<(NG+1+255)/256,256,0,stream>>>(batch, i_goff);
  prep_cg<<<1,128,0,stream>>>(Wg1, w_cg);
  colvec<<<1,128,0,stream>>>(Wm, att_dst_m, w_vmd);
  pack_all<<<dim3(24,14),256,0,stream>>>(W1, Wg1, Wg2, Wa, Wm, Wih0, Whh0,
                                         Wih_a, Whh_a, Wih_m, Whh_m, w_pack);

  const int GB = (NN+31)/32;     // gemm_direct blocks
  const int FB = (NN+15)/16;     // fused_gru blocks
  const int wavegrid_g = (NG*64)/256;

  // x = leaky(x @ W1.T + b1)
  gemm_direct<64><<<GB,256,0,stream>>>(x_in, pk_W1, b1, f_x, nullptr,
                                       nullptr,nullptr,nullptr,nullptr,nullptr, NN, 1);

  float* cur = f_x;
  float* nxt = f_xb;

  // ---- GATEConv: xe-GEMM fused with s1=xe.att_l and s2=x.att_r; no C write ----
  gemm_direct<128><<<GB,256,0,stream>>>(cur, pk_g1, w_cg, nullptr, nullptr,
                                        att_l, nullptr, att_r, f_s1, f_s2, NN, 1);
  gemm_direct<128><<<GB,256,0,stream>>>(cur, pk_g2, nullptr, nullptr, f_t,
                                        nullptr,nullptr,nullptr,nullptr,nullptr, NN, 0);
  agg_edges<<<(NN+3)/4,256,0,stream>>>(i_off, i_src, f_s1, f_s2, f_t, bg, f_h, NN);
  fused_gru<<<FB,256,0,stream>>>(f_h, cur, pk_wih0, pk_whh0, bih0, bhh0, nxt, NN);
  { float* t=cur; cur=nxt; nxt=t; }

  // ---- 2x GATConv + GRU ----
  for (int l=0;l<2;l++){
    gemm_direct<128><<<GB,256,0,stream>>>(cur, l ? pk_wa1 : pk_wa0, nullptr, nullptr, f_t,
                                          att_src_a + l*HID, att_dst_a + l*HID, nullptr,
                                          f_s1, f_s2, NN, 0);
    agg_edges<<<(NN+3)/4,256,0,stream>>>(i_off, i_src, f_s1, f_s2, f_t, ba + l*HID, f_h, NN);
    fused_gru<<<FB,256,0,stream>>>(f_h, cur,
                                   l ? pk_wiha1 : pk_wiha0, l ? pk_whha1 : pk_whha0,
                                   bih_a + l*384, bhh_a + l*384, nxt, NN);
    { float* t=cur; cur=nxt; nxt=t; }
  }

  // ---- attentive readout ----
  graph_sum<<<wavegrid_g,256,0,stream>>>(i_goff, cur, g_o0);
  gemm_direct<128><<<GB,256,0,stream>>>(cur, pk_wm, nullptr, nullptr, f_t,
                                        att_src_m, nullptr, nullptr, f_s1, nullptr, NN, 0);
  float* gc = g_o0; float* gn = g_o1;
  for (int t=0;t<3;t++){
    graph_soft2<<<wavegrid_g,256,0,stream>>>(i_goff, f_s1, gc, w_vmd, f_t, bm, g_h);
    fused_gru<<<(NG+15)/16,256,0,stream>>>(g_h, gc, pk_wihm, pk_whhm, bih_m, bhh_m, gn, NG);
    { float* tt=gc; gc=gn; gn=tt; }
  }

  rowdot<<<wavegrid_g,256,0,stream>>>(gc, W2, b2, (float*)d_out, NG);
}